// Round 6
// baseline (827.994 us; speedup 1.0000x reference)
//
#include <hip/hip_runtime.h>
#include <math.h>

#define S_ 16
#define M_ 256
#define NF_ 4096
#define OUT_ 256
#define ROWS_ (M_ + NF_)     // 4352
#define JITTER_ 1e-8f
#define MM_ (M_ * M_)        // 65536

typedef unsigned short u16;
typedef __attribute__((ext_vector_type(8))) short bf16x8;
typedef __attribute__((ext_vector_type(4))) float f32x4;

// ---------------- small prep kernels ----------------

__global__ void max1_kernel(const float* __restrict__ x, int n, float* part) {
    __shared__ float red[256];
    int tid = threadIdx.x;
    float m = -3.4e38f;
    for (int i = blockIdx.x * blockDim.x + tid; i < n; i += gridDim.x * blockDim.x)
        m = fmaxf(m, x[i]);
    red[tid] = m; __syncthreads();
    for (int s = 128; s > 0; s >>= 1) {
        if (tid < s) red[tid] = fmaxf(red[tid], red[tid + s]);
        __syncthreads();
    }
    if (tid == 0) part[blockIdx.x] = red[0];
}

__global__ void max2_kernel(const float* part, float* ws) {
    __shared__ float red[256];
    int tid = threadIdx.x;
    red[tid] = part[tid]; __syncthreads();
    for (int s = 128; s > 0; s >>= 1) {
        if (tid < s) red[tid] = fmaxf(red[tid], red[tid + s]);
        __syncthreads();
    }
    if (tid == 0) { ws[0] = red[0]; ws[2] = JITTER_ * red[0]; }
}

__global__ void prep_kernel(const float* __restrict__ Lloc, const float* __restrict__ Lscale, float* ws) {
    __shared__ float red[256];
    int tid = threadIdx.x;
    red[tid] = Lloc[tid * M_ + tid];
    __syncthreads();
    for (int s = 128; s > 0; s >>= 1) {
        if (tid < s) red[tid] += red[tid + s];
        __syncthreads();
    }
    if (tid == 0) {
        float norm = red[0] / (float)M_;
        ws[1] = expf(Lscale[0]) / norm;
    }
}

__global__ void scaleL_kernel(const float* __restrict__ Lloc, const float* __restrict__ ws, float* __restrict__ L) {
    int i = blockIdx.x * blockDim.x + threadIdx.x;
    if (i < MM_) L[i] = Lloc[i] * ws[1];
}

__global__ void copyjit_kernel(const float* __restrict__ Kuu, const float* __restrict__ ws, float* __restrict__ dst) {
    int i = blockIdx.x * blockDim.x + threadIdx.x;
    if (i < S_ * MM_) {
        float v = Kuu[i];
        int r = (i >> 8) & 255;
        int c = i & 255;
        if (r == c) v += ws[2];
        dst[i] = v;
    }
}

// ---------------- batched blocked Cholesky (BK=16, 1024 threads) ----------------

__global__ __launch_bounds__(1024) void chol_kernel(float* bufA, float* bufB) {
    int blk = blockIdx.x;                       // 0..31
    float* Ag = (blk < S_) ? (bufA + (long)blk * MM_) : (bufB + (long)(blk - S_) * MM_);
    __shared__ float P[33280];                  // 133120 B
    __shared__ float panT[16][256];             // 16 KB, [panel col][global row]
    __shared__ float piv[16][18];               // [j][i<j]=L[k0+j][i]; [j][16]=1/d_j
    float4* P4 = (float4*)P;
    int tid = threadIdx.x;                      // 0..1023
    int r = tid >> 2, s = tid & 3;              // row, sub
    int lane = tid & 63, wid = tid >> 6;        // wave w holds rows 16w..16w+15
    int mg = r >> 2, tg = r & 3;
    int b4 = (mg + 1) * (2 * mg + tg);          // float4 base of row r

    for (int i = wid; i < M_; i += 16) {
        int m = i >> 2, t4 = i & 3;
        int rb4 = (m + 1) * (2 * m + t4);
        if (lane <= m) P4[rb4 + lane] = ((const float4*)Ag)[i * 64 + lane];
    }
    __syncthreads();

    float preg[16];
    for (int p = 0; p < 16; p++) {
        int k0 = p << 4;
        int c0 = p << 2;
        #pragma unroll
        for (int rr = 0; rr < 4; rr++) {
            float4 v = make_float4(0.f, 0.f, 0.f, 0.f);
            if (r >= k0 && c0 + rr <= mg) v = P4[b4 + c0 + rr];
            preg[4 * rr + 0] = v.x; preg[4 * rr + 1] = v.y;
            preg[4 * rr + 2] = v.z; preg[4 * rr + 3] = v.w;
        }
        if (wid == p) {
            int dj = lane >> 2;                 // row offset in block
            float myinv = 0.f;
            #pragma unroll
            for (int j = 0; j < 16; j++) {
                float app = __shfl(preg[j], 4 * j, 64);
                float d = sqrtf(app);
                float inv = 1.0f / d;
                if (dj == j) { preg[j] = d; myinv = inv; }
                else if (dj > j) preg[j] *= inv;
                #pragma unroll
                for (int j2 = j + 1; j2 < 16; j2++) {
                    float Lj2 = __shfl(preg[j], 4 * j2, 64);
                    if (dj >= j2) preg[j2] -= preg[j] * Lj2;
                }
            }
            if (s == 0) {
                #pragma unroll
                for (int i = 0; i < 16; i++) piv[dj][i] = preg[i];
                piv[dj][16] = myinv;
            }
        }
        __syncthreads();
        if (r > k0 + 15) {
            float x[16];
            #pragma unroll
            for (int j = 0; j < 16; j++) {
                float acc = preg[j];
                #pragma unroll
                for (int i = 0; i < 16; i++)
                    if (i < j) acc -= x[i] * piv[j][i];
                x[j] = acc * piv[j][16];
            }
            #pragma unroll
            for (int j = 0; j < 16; j++) preg[j] = x[j];
        }
        if (r >= k0) {
            #pragma unroll
            for (int j = 0; j < 4; j++) panT[4 * s + j][r] = preg[4 * s + j];
            int c = c0 + s;
            if (c <= mg)
                P4[b4 + c] = make_float4(preg[4 * s], preg[4 * s + 1],
                                         preg[4 * s + 2], preg[4 * s + 3]);
        }
        __syncthreads();
        if (r > k0 + 15) {
            for (int c = c0 + 4 + s; c <= mg; c += 4) {
                float4 rv = P4[b4 + c];
                #pragma unroll
                for (int tt = 0; tt < 16; tt++) {
                    float4 pv = *(const float4*)&panT[tt][c << 2];
                    rv.x -= preg[tt] * pv.x;
                    rv.y -= preg[tt] * pv.y;
                    rv.z -= preg[tt] * pv.z;
                    rv.w -= preg[tt] * pv.w;
                }
                P4[b4 + c] = rv;
            }
        }
        __syncthreads();
    }

    for (int i = wid; i < M_; i += 16) {
        int m = i >> 2, t4 = i & 3;
        int rb4 = (m + 1) * (2 * m + t4);
        if (lane <= m) ((float4*)Ag)[i * 64 + lane] = P4[rb4 + lane];
    }
}

// ---------------- batched blocked triangular inverse (BK=16) ----------------

__global__ __launch_bounds__(256) void trinv_kernel(const float* bufA, const float* bufB,
                                                    float* TA_, float* TB_) {
    int mat = blockIdx.y;      // 0..31
    int cb  = blockIdx.x;      // 0..3 -> columns cb*64 .. cb*64+63
    const float* Lg = (mat < S_) ? (bufA + (long)mat * MM_) : (bufB + (long)(mat - S_) * MM_);
    float* Tg       = (mat < S_) ? (TA_ + (long)mat * MM_) : (TB_ + (long)(mat - S_) * MM_);
    __shared__ float X[M_ * 65];       // [k][c]
    __shared__ float panR[M_ * 20];    // [k][j], stride 20
    int tid = threadIdx.x;
    int c = tid & 63, q = tid >> 6;
    int jglob = cb * 64 + c;

    for (int idx = tid; idx < M_ * 65; idx += 256) X[idx] = 0.f;
    __syncthreads();
    if (q == 0) X[jglob * 65 + c] = 1.0f;

    int p0 = cb * 4;
    for (int p = p0; p < 16; p++) {
        int t0 = p << 4;
        int k = t0 + tid;
        if (k < M_) {
            const float4* src = (const float4*)&Lg[(long)k * M_ + t0];
            float4* dst = (float4*)&panR[k * 20];
            dst[0] = src[0]; dst[1] = src[1]; dst[2] = src[2]; dst[3] = src[3];
        }
        __syncthreads();
        if (q == (t0 >> 6)) {
            float xr[16];
            #pragma unroll
            for (int j = 0; j < 16; j++) {
                float xv = X[(t0 + j) * 65 + c];
                #pragma unroll
                for (int i = 0; i < 16; i++)
                    if (i < j) xv -= panR[(t0 + j) * 20 + i] * xr[i];
                xv *= (1.0f / panR[(t0 + j) * 20 + j]);
                xr[j] = xv;
                X[(t0 + j) * 65 + c] = xv;
            }
        }
        __syncthreads();
        int kbeg = q << 6; if (kbeg < t0 + 16) kbeg = t0 + 16;
        int kend = (q << 6) + 64;
        if (kbeg < kend) {
            float xr[16];
            #pragma unroll
            for (int j = 0; j < 16; j++) xr[j] = X[(t0 + j) * 65 + c];
            for (int kk = kbeg; kk < kend; kk++) {
                float rv = X[kk * 65 + c];
                const float4* pr = (const float4*)&panR[kk * 20];
                float4 a = pr[0], b = pr[1], d = pr[2], e = pr[3];
                rv -= a.x * xr[0] + a.y * xr[1] + a.z * xr[2] + a.w * xr[3];
                rv -= b.x * xr[4] + b.y * xr[5] + b.z * xr[6] + b.w * xr[7];
                rv -= d.x * xr[8] + d.y * xr[9] + d.z * xr[10] + d.w * xr[11];
                rv -= e.x * xr[12] + e.y * xr[13] + e.z * xr[14] + e.w * xr[15];
                X[kk * 65 + c] = rv;
            }
        }
        __syncthreads();
    }

    for (int idx = tid; idx < M_ * 64; idx += 256) {
        int k = idx >> 6, cc = idx & 63;
        Tg[(long)k * M_ + cb * 64 + cc] = X[k * 65 + cc];
    }
}

// ---------------- MFMA bf16x3 split-precision GEMM ----------------
// C = alpha*opA(A)@opB(B) [+ C if ACC] [+ dcoef*D] [+ I if addI]
// [+ vf[row]*noise[row*256+col] if EF].  K is always 256.
// fp32 operands split x = hi + lo (RN bf16 each); product via 3 MFMAs:
// hi*hi + hi*lo + lo*hi  (residual ~2^-16 relative).
// Tile 128x128, 4 waves 2x2, each wave 4x4 frags of mfma_f32_16x16x32_bf16.
// Verified C/D layout: col = lane&15, row = (lane>>4)*4 + reg.

struct GemmParams {
    const float* A; const float* B; float* C;
    const float* D;
    const float* vf; const float* noise;
    int M, N, K;
    int lda, ldb, ldc;
    long sA, sB, sC, sD;
    float alpha, dcoef;
    int addI;
    long sVf, sNoise;
};

__device__ inline void cvt2(float x, u16& h, u16& l) {
    unsigned xb = __float_as_uint(x);
    unsigned hb = (xb + 0x7fffu + ((xb >> 16) & 1u)) >> 16;
    float fh = __uint_as_float(hb << 16);
    float rr = x - fh;
    unsigned rb = __float_as_uint(rr);
    unsigned lb = (rb + 0x7fffu + ((rb >> 16) & 1u)) >> 16;
    h = (u16)hb; l = (u16)lb;
}

template<int TAf, int TBf, int ACCf, int EFf>
__global__ __launch_bounds__(256) void mgemm_k(GemmParams p) {
    int bz = blockIdx.z;
    const float* A = p.A + (long)bz * p.sA;
    const float* B = p.B + (long)bz * p.sB;
    float* C = p.C + (long)bz * p.sC;
    int bm = blockIdx.y * 128, bn = blockIdx.x * 128;
    __shared__ __align__(16) u16 Ah[128][40];
    __shared__ __align__(16) u16 Al[128][40];
    __shared__ __align__(16) u16 Bh[128][40];
    __shared__ __align__(16) u16 Bl[128][40];
    int tid = threadIdx.x;
    int lane = tid & 63, wid = tid >> 6;
    int wm = (wid >> 1) << 6, wn = (wid & 1) << 6;
    f32x4 acc[4][4];
    #pragma unroll
    for (int m = 0; m < 4; m++)
        #pragma unroll
        for (int n = 0; n < 4; n++)
            acc[m][n] = (f32x4){0.f, 0.f, 0.f, 0.f};

    for (int k0 = 0; k0 < 256; k0 += 32) {
        // ---- stage A tile (128 rows x 32 k) as hi/lo bf16 ----
        if (TAf == 0) {       // opA(i,k)=A[i*lda+k], contiguous in k
            int row = tid >> 1, kh = (tid & 1) << 4;
            int grow = bm + row; if (grow >= p.M) grow = p.M - 1;
            const float* src = A + (long)grow * p.lda + k0 + kh;
            u16 h[16], l[16];
            #pragma unroll
            for (int j = 0; j < 16; j += 4) {
                float4 v = *(const float4*)(src + j);
                cvt2(v.x, h[j], l[j]); cvt2(v.y, h[j+1], l[j+1]);
                cvt2(v.z, h[j+2], l[j+2]); cvt2(v.w, h[j+3], l[j+3]);
            }
            uint4 q0, q1;
            q0.x = h[0] | ((unsigned)h[1] << 16); q0.y = h[2] | ((unsigned)h[3] << 16);
            q0.z = h[4] | ((unsigned)h[5] << 16); q0.w = h[6] | ((unsigned)h[7] << 16);
            q1.x = h[8] | ((unsigned)h[9] << 16); q1.y = h[10] | ((unsigned)h[11] << 16);
            q1.z = h[12] | ((unsigned)h[13] << 16); q1.w = h[14] | ((unsigned)h[15] << 16);
            *(uint4*)&Ah[row][kh] = q0; *(uint4*)&Ah[row][kh + 8] = q1;
            q0.x = l[0] | ((unsigned)l[1] << 16); q0.y = l[2] | ((unsigned)l[3] << 16);
            q0.z = l[4] | ((unsigned)l[5] << 16); q0.w = l[6] | ((unsigned)l[7] << 16);
            q1.x = l[8] | ((unsigned)l[9] << 16); q1.y = l[10] | ((unsigned)l[11] << 16);
            q1.z = l[12] | ((unsigned)l[13] << 16); q1.w = l[14] | ((unsigned)l[15] << 16);
            *(uint4*)&Al[row][kh] = q0; *(uint4*)&Al[row][kh + 8] = q1;
        } else {              // opA(i,k)=A[k*lda+i], contiguous in i
            int k = tid >> 3, ih = (tid & 7) << 4;
            bool ok = (bm + ih) < p.M;
            const float* src = A + (long)(k0 + k) * p.lda + (ok ? (bm + ih) : 0);
            #pragma unroll
            for (int j = 0; j < 16; j += 4) {
                float4 v = *(const float4*)(src + j);
                u16 h, l;
                cvt2(v.x, h, l); Ah[ih + j][k] = h;     Al[ih + j][k] = l;
                cvt2(v.y, h, l); Ah[ih + j + 1][k] = h; Al[ih + j + 1][k] = l;
                cvt2(v.z, h, l); Ah[ih + j + 2][k] = h; Al[ih + j + 2][k] = l;
                cvt2(v.w, h, l); Ah[ih + j + 3][k] = h; Al[ih + j + 3][k] = l;
            }
        }
        // ---- stage B tile (32 k x 128 cols) transposed to [col][k] ----
        if (TBf == 0) {       // opB(k,j)=B[k*ldb+j], contiguous in j
            int k = tid >> 3, jh = (tid & 7) << 4;
            bool ok = (bn + jh) < p.N;
            const float* src = B + (long)(k0 + k) * p.ldb + (ok ? (bn + jh) : 0);
            #pragma unroll
            for (int j = 0; j < 16; j += 4) {
                float4 v = *(const float4*)(src + j);
                u16 h, l;
                cvt2(v.x, h, l); Bh[jh + j][k] = h;     Bl[jh + j][k] = l;
                cvt2(v.y, h, l); Bh[jh + j + 1][k] = h; Bl[jh + j + 1][k] = l;
                cvt2(v.z, h, l); Bh[jh + j + 2][k] = h; Bl[jh + j + 2][k] = l;
                cvt2(v.w, h, l); Bh[jh + j + 3][k] = h; Bl[jh + j + 3][k] = l;
            }
        } else {              // opB(k,j)=B[j*ldb+k], contiguous in k
            int col = tid >> 1, kh = (tid & 1) << 4;
            int gcol = bn + col; if (gcol >= p.N) gcol = p.N - 1;
            const float* src = B + (long)gcol * p.ldb + k0 + kh;
            u16 h[16], l[16];
            #pragma unroll
            for (int j = 0; j < 16; j += 4) {
                float4 v = *(const float4*)(src + j);
                cvt2(v.x, h[j], l[j]); cvt2(v.y, h[j+1], l[j+1]);
                cvt2(v.z, h[j+2], l[j+2]); cvt2(v.w, h[j+3], l[j+3]);
            }
            uint4 q0, q1;
            q0.x = h[0] | ((unsigned)h[1] << 16); q0.y = h[2] | ((unsigned)h[3] << 16);
            q0.z = h[4] | ((unsigned)h[5] << 16); q0.w = h[6] | ((unsigned)h[7] << 16);
            q1.x = h[8] | ((unsigned)h[9] << 16); q1.y = h[10] | ((unsigned)h[11] << 16);
            q1.z = h[12] | ((unsigned)h[13] << 16); q1.w = h[14] | ((unsigned)h[15] << 16);
            *(uint4*)&Bh[col][kh] = q0; *(uint4*)&Bh[col][kh + 8] = q1;
            q0.x = l[0] | ((unsigned)l[1] << 16); q0.y = l[2] | ((unsigned)l[3] << 16);
            q0.z = l[4] | ((unsigned)l[5] << 16); q0.w = l[6] | ((unsigned)l[7] << 16);
            q1.x = l[8] | ((unsigned)l[9] << 16); q1.y = l[10] | ((unsigned)l[11] << 16);
            q1.z = l[12] | ((unsigned)l[13] << 16); q1.w = l[14] | ((unsigned)l[15] << 16);
            *(uint4*)&Bl[col][kh] = q0; *(uint4*)&Bl[col][kh + 8] = q1;
        }
        __syncthreads();
        // ---- MFMA: one K=32 step ----
        int fr = lane & 15, ko = (lane >> 4) << 3;
        bf16x8 ah[4], al[4], bh[4], bl[4];
        #pragma unroll
        for (int m = 0; m < 4; m++) {
            ah[m] = *(const bf16x8*)&Ah[wm + m * 16 + fr][ko];
            al[m] = *(const bf16x8*)&Al[wm + m * 16 + fr][ko];
        }
        #pragma unroll
        for (int n = 0; n < 4; n++) {
            bh[n] = *(const bf16x8*)&Bh[wn + n * 16 + fr][ko];
            bl[n] = *(const bf16x8*)&Bl[wn + n * 16 + fr][ko];
        }
        #pragma unroll
        for (int m = 0; m < 4; m++)
            #pragma unroll
            for (int n = 0; n < 4; n++) {
                acc[m][n] = __builtin_amdgcn_mfma_f32_16x16x32_bf16(ah[m], bh[n], acc[m][n], 0, 0, 0);
                acc[m][n] = __builtin_amdgcn_mfma_f32_16x16x32_bf16(ah[m], bl[n], acc[m][n], 0, 0, 0);
                acc[m][n] = __builtin_amdgcn_mfma_f32_16x16x32_bf16(al[m], bh[n], acc[m][n], 0, 0, 0);
            }
        __syncthreads();
    }

    // ---- epilogue ----
    int fr = lane & 15, rq = (lane >> 4) << 2;
    #pragma unroll
    for (int m = 0; m < 4; m++) {
        int row0 = bm + wm + m * 16 + rq;
        #pragma unroll
        for (int n = 0; n < 4; n++) {
            int col = bn + wn + n * 16 + fr;
            if (col < p.N) {
                #pragma unroll
                for (int i = 0; i < 4; i++) {
                    int r = row0 + i;
                    if (r < p.M) {
                        float val = p.alpha * acc[m][n][i];
                        long cidx = (long)r * p.ldc + col;
                        if (ACCf) val += C[cidx];
                        if (p.D)  val += p.dcoef * p.D[(long)bz * p.sD + (long)r * p.ldc + col];
                        if (p.addI && r == col) val += 1.0f;
                        if (EFf)  val += p.vf[(long)bz * p.sVf + r] *
                                         p.noise[(long)bz * p.sNoise + (long)r * 256 + col];
                        C[cidx] = val;
                    }
                }
            }
        }
    }
}

// ---------------- Vf = sqrt(Kff_diag - sum_m A*Kuf) ----------------

__global__ void vf_kernel(const float* __restrict__ Achunk, const float* __restrict__ Kuf,
                          const float* __restrict__ Kff, float* __restrict__ Vf,
                          int f0, int nfc) {
    int s = blockIdx.y;
    int fl = blockIdx.x * 256 + threadIdx.x;
    if (fl >= nfc) return;
    const float* Ab = Achunk + (long)s * M_ * nfc;
    const float* Kb = Kuf + (long)s * M_ * NF_ + f0;
    float acc = 0.f;
    for (int m = 0; m < M_; m++)
        acc += Ab[(long)m * nfc + fl] * Kb[(long)m * NF_ + fl];
    float v = Kff[(long)s * NF_ + f0 + fl] - acc;
    Vf[(long)s * NF_ + f0 + fl] = sqrtf(fmaxf(v, 0.f));
}

__global__ void ucopy_kernel(const float* __restrict__ U, float* __restrict__ out) {
    int i = blockIdx.x * blockDim.x + threadIdx.x;
    if (i < S_ * M_ * OUT_) {
        int s = i >> 16;
        int rc = i & 65535;
        out[(long)s * ROWS_ * OUT_ + rc] = U[i];
    }
}

// ---------------- host ----------------

extern "C" void kernel_launch(void* const* d_in, const int* in_sizes, int n_in,
                              void* d_out, int out_size, void* d_ws, size_t ws_size,
                              hipStream_t stream) {
    const float* Kuu       = (const float*)d_in[0];
    const float* Kuf       = (const float*)d_in[1];
    const float* Kff       = (const float*)d_in[2];
    const float* Lloc      = (const float*)d_in[3];
    const float* Lscale    = (const float*)d_in[4];
    const float* u_param   = (const float*)d_in[5];
    const float* noise_inv = (const float*)d_in[6];
    const float* noise_L   = (const float*)d_in[7];
    const float* noise_f   = (const float*)d_in[8];
    float* out = (float*)d_out;
    float* ws  = (float*)d_ws;

    long off = 1024;
    float* part   = ws + 16;
    float* Lbuf   = ws + off; off += MM_;
    float* UPt    = ws + off; off += MM_;
    float* UP     = ws + off; off += MM_;
    float* Vf     = ws + off; off += (long)S_ * NF_;
    float* cholK  = ws + off; off += (long)S_ * MM_;
    float* TK     = ws + off; off += (long)S_ * MM_;
    float* KuuL   = ws + off; off += (long)S_ * MM_;
    float* choll  = ws + off; off += (long)S_ * MM_;
    float* Tl     = ws + off; off += (long)S_ * MM_;
    float* KuuInv = ws + off; off += (long)S_ * MM_;
    float* lKlpIi = ws + off; off += (long)S_ * MM_;
    float* Stmp   = ws + off; off += (long)S_ * MM_;
    float* Sigma  = ws + off; off += (long)S_ * MM_;
    float* RHS    = ws + off; off += (long)S_ * MM_;
    float* U      = ws + off; off += (long)S_ * MM_;
    float* Achunk = ws + off;
    long avail = (long)(ws_size / 4) - off;
    int nfc = (int)(avail / ((long)S_ * M_));
    nfc = (nfc / 64) * 64;
    if (nfc > NF_) nfc = NF_;
    if (nfc < 64) nfc = 64;

    dim3 b256(256);

    auto run = [&](const float* A, const float* B, float* C,
                   int Mm, int Nn, int Kk, int lda, int ldb, int ldc,
                   long sA, long sB, long sC,
                   int TAf, int TBf, int ACCf, float alpha,
                   const float* D, long sD, float dcoef, int addI,
                   const float* vfp, long sVf, const float* noisep, long sNoise, int EFf,
                   int batch) {
        GemmParams q;
        q.A = A; q.B = B; q.C = C; q.D = D; q.vf = vfp; q.noise = noisep;
        q.M = Mm; q.N = Nn; q.K = Kk; q.lda = lda; q.ldb = ldb; q.ldc = ldc;
        q.sA = sA; q.sB = sB; q.sC = sC; q.sD = sD;
        q.alpha = alpha; q.dcoef = dcoef; q.addI = addI;
        q.sVf = sVf; q.sNoise = sNoise;
        dim3 g((Nn + 127) / 128, (Mm + 127) / 128, batch);
        if (EFf)                mgemm_k<1,0,0,1><<<g, b256, 0, stream>>>(q);
        else if (ACCf)          mgemm_k<0,1,1,0><<<g, b256, 0, stream>>>(q);
        else if (TAf && TBf)    mgemm_k<1,1,0,0><<<g, b256, 0, stream>>>(q);
        else if (TAf)           mgemm_k<1,0,0,0><<<g, b256, 0, stream>>>(q);
        else if (TBf)           mgemm_k<0,1,0,0><<<g, b256, 0, stream>>>(q);
        else                    mgemm_k<0,0,0,0><<<g, b256, 0, stream>>>(q);
    };

    // scalars
    max1_kernel<<<256, b256, 0, stream>>>(Kuu, S_ * MM_, part);
    max2_kernel<<<1, b256, 0, stream>>>(part, ws);
    prep_kernel<<<1, b256, 0, stream>>>(Lloc, Lscale, ws);
    scaleL_kernel<<<256, b256, 0, stream>>>(Lloc, ws, Lbuf);
    copyjit_kernel<<<4096, b256, 0, stream>>>(Kuu, ws, cholK);

    // KuuL = Kuu @ L
    run(Kuu, Lbuf, KuuL, 256,256,256, 256,256,256, MM_,0,MM_, 0,0,0, 1.f,
        nullptr,0,0.f,0, nullptr,0,nullptr,0,0, S_);
    // lKlpI = L^T @ KuuL + I   (into choll buffer)
    run(Lbuf, KuuL, choll, 256,256,256, 256,256,256, 0,MM_,MM_, 1,0,0, 1.f,
        nullptr,0,0.f,1, nullptr,0,nullptr,0,0, S_);

    chol_kernel<<<32, dim3(1024), 0, stream>>>(cholK, choll);
    trinv_kernel<<<dim3(4, 32), b256, 0, stream>>>(cholK, choll, TK, Tl);

    // KuuInv = TK^T @ TK ; lKlpIinv = Tl^T @ Tl
    run(TK, TK, KuuInv, 256,256,256, 256,256,256, MM_,MM_,MM_, 1,0,0, 1.f,
        nullptr,0,0.f,0, nullptr,0,nullptr,0,0, S_);
    run(Tl, Tl, lKlpIi, 256,256,256, 256,256,256, MM_,MM_,MM_, 1,0,0, 1.f,
        nullptr,0,0.f,0, nullptr,0,nullptr,0,0, S_);
    // Stmp = KuuL @ lKlpIinv
    run(KuuL, lKlpIi, Stmp, 256,256,256, 256,256,256, MM_,MM_,MM_, 0,0,0, 1.f,
        nullptr,0,0.f,0, nullptr,0,nullptr,0,0, S_);
    // Sigma = Kuu - Stmp @ KuuL^T
    run(Stmp, KuuL, Sigma, 256,256,256, 256,256,256, MM_,MM_,MM_, 0,1,0, -1.f,
        Kuu,MM_,1.f,0, nullptr,0,nullptr,0,0, S_);

    // UP = L @ (L^T @ u_param^T)   (batch 1)
    run(Lbuf, u_param, UPt, 256,256,256, 256,256,256, 0,0,0, 1,1,0, 1.f,
        nullptr,0,0.f,0, nullptr,0,nullptr,0,0, 1);
    run(Lbuf, UPt, UP, 256,256,256, 256,256,256, 0,0,0, 0,0,0, 1.f,
        nullptr,0,0.f,0, nullptr,0,nullptr,0,0, 1);

    // RHS = TK^T @ noise_inv^T + UP
    run(TK, noise_inv, RHS, 256,256,256, 256,256,256, MM_,MM_,MM_, 1,1,0, 1.f,
        UP,0,1.f,0, nullptr,0,nullptr,0,0, S_);
    // RHS += L @ noise_L^T
    run(Lbuf, noise_L, RHS, 256,256,256, 256,256,256, 0,MM_,MM_, 0,1,1, 1.f,
        nullptr,0,0.f,0, nullptr,0,nullptr,0,0, S_);
    // U = Sigma @ RHS
    run(Sigma, RHS, U, 256,256,256, 256,256,256, MM_,MM_,MM_, 0,0,0, 1.f,
        nullptr,0,0.f,0, nullptr,0,nullptr,0,0, S_);

    ucopy_kernel<<<4096, b256, 0, stream>>>(U, out);

    for (int f0 = 0; f0 < NF_; f0 += nfc) {
        int w = NF_ - f0; if (w > nfc) w = nfc;
        // A = KuuInv @ Kuf[:, f0:f0+w]
        run(KuuInv, Kuf + f0, Achunk, 256, w, 256, 256, NF_, w,
            MM_, (long)M_ * NF_, (long)M_ * w, 0,0,0, 1.f,
            nullptr,0,0.f,0, nullptr,0,nullptr,0,0, S_);
        // sqrt(Vf)
        vf_kernel<<<dim3((w + 255) / 256, S_), b256, 0, stream>>>(Achunk, Kuf, Kff, Vf, f0, w);
        // out_f = A^T @ U + sqrt(Vf)*noise_f
        run(Achunk, U, out + (long)(M_ + f0) * OUT_, w, 256, 256, w, 256, 256,
            (long)M_ * w, MM_, (long)ROWS_ * OUT_, 1,0,0, 1.f,
            nullptr,0,0.f,0, Vf + f0, NF_, noise_f + (long)f0 * OUT_, (long)NF_ * OUT_, 1, S_);
    }
}

// Round 7
// 608.962 us; speedup vs baseline: 1.3597x; 1.3597x over previous
//
#include <hip/hip_runtime.h>
#include <math.h>

#define S_ 16
#define M_ 256
#define NF_ 4096
#define OUT_ 256
#define ROWS_ (M_ + NF_)     // 4352
#define JITTER_ 1e-8f
#define MM_ (M_ * M_)        // 65536

typedef unsigned short u16;
typedef __attribute__((ext_vector_type(8))) short bf16x8;
typedef __attribute__((ext_vector_type(4))) float f32x4;

__device__ inline void cvt2(float x, u16& h, u16& l) {
    unsigned xb = __float_as_uint(x);
    unsigned hb = (xb + 0x7fffu + ((xb >> 16) & 1u)) >> 16;
    float fh = __uint_as_float(hb << 16);
    float rr = x - fh;
    unsigned rb = __float_as_uint(rr);
    unsigned lb = (rb + 0x7fffu + ((rb >> 16) & 1u)) >> 16;
    h = (u16)hb; l = (u16)lb;
}
__device__ inline float bfa(u16 v) { return __uint_as_float(((unsigned)v) << 16); }

// ---------------- small prep kernels ----------------

__global__ void max1_kernel(const float* __restrict__ x, int n, float* part) {
    __shared__ float red[256];
    int tid = threadIdx.x;
    float m = -3.4e38f;
    for (int i = blockIdx.x * blockDim.x + tid; i < n; i += gridDim.x * blockDim.x)
        m = fmaxf(m, x[i]);
    red[tid] = m; __syncthreads();
    for (int s = 128; s > 0; s >>= 1) {
        if (tid < s) red[tid] = fmaxf(red[tid], red[tid + s]);
        __syncthreads();
    }
    if (tid == 0) part[blockIdx.x] = red[0];
}

__global__ void max2_kernel(const float* part, float* ws) {
    __shared__ float red[256];
    int tid = threadIdx.x;
    red[tid] = part[tid]; __syncthreads();
    for (int s = 128; s > 0; s >>= 1) {
        if (tid < s) red[tid] = fmaxf(red[tid], red[tid + s]);
        __syncthreads();
    }
    if (tid == 0) { ws[0] = red[0]; ws[2] = JITTER_ * red[0]; }
}

__global__ void prep_kernel(const float* __restrict__ Lloc, const float* __restrict__ Lscale, float* ws) {
    __shared__ float red[256];
    int tid = threadIdx.x;
    red[tid] = Lloc[tid * M_ + tid];
    __syncthreads();
    for (int s = 128; s > 0; s >>= 1) {
        if (tid < s) red[tid] += red[tid + s];
        __syncthreads();
    }
    if (tid == 0) {
        float norm = red[0] / (float)M_;
        ws[1] = expf(Lscale[0]) / norm;
    }
}

__global__ void copyjit_kernel(const float* __restrict__ Kuu, const float* __restrict__ ws, float* __restrict__ dst) {
    int i = blockIdx.x * blockDim.x + threadIdx.x;
    if (i < S_ * MM_) {
        float v = Kuu[i];
        int r = (i >> 8) & 255;
        int c = i & 255;
        if (r == c) v += ws[2];
        dst[i] = v;
    }
}

// ---- plain split: fp32 -> bf16 hi/lo (optional scale from device ptr) ----
__global__ void psplit_kernel(const float* __restrict__ src, u16* __restrict__ h,
                              u16* __restrict__ l, long n, const float* scaleptr) {
    float sc = scaleptr ? scaleptr[0] : 1.0f;
    long stride = (long)gridDim.x * blockDim.x * 4;
    for (long i = ((long)blockIdx.x * blockDim.x + threadIdx.x) * 4; i < n; i += stride) {
        float4 v = *(const float4*)(src + i);
        u16 h0,h1,h2,h3,l0,l1,l2,l3;
        cvt2(v.x*sc,h0,l0); cvt2(v.y*sc,h1,l1); cvt2(v.z*sc,h2,l2); cvt2(v.w*sc,h3,l3);
        ushort4 hv = {h0,h1,h2,h3}, lv = {l0,l1,l2,l3};
        *(ushort4*)(h + i) = hv;
        *(ushort4*)(l + i) = lv;
    }
}

// ---- transpose split: src[r][c] (ldS) -> dst[c][r] (ldD) bf16 hi/lo ----
__global__ void tsplit_kernel(const float* __restrict__ src, int ldS, long sS,
                              u16* __restrict__ h, u16* __restrict__ l, int ldD, long sD,
                              const float* scaleptr) {
    int b = blockIdx.z;
    src += (long)b * sS; h += (long)b * sD; l += (long)b * sD;
    __shared__ float T[32][33];
    int r0 = blockIdx.y * 32, c0 = blockIdx.x * 32;
    float sc = scaleptr ? scaleptr[0] : 1.0f;
    int tid = threadIdx.x;
    int lrow = tid >> 3, lc4 = (tid & 7) * 4;
    float4 v = *(const float4*)(src + (long)(r0 + lrow) * ldS + c0 + lc4);
    T[lrow][lc4 + 0] = v.x * sc; T[lrow][lc4 + 1] = v.y * sc;
    T[lrow][lc4 + 2] = v.z * sc; T[lrow][lc4 + 3] = v.w * sc;
    __syncthreads();
    int wcol = tid >> 3, wr4 = (tid & 7) * 4;
    u16 h0,h1,h2,h3,l0,l1,l2,l3;
    cvt2(T[wr4+0][wcol],h0,l0); cvt2(T[wr4+1][wcol],h1,l1);
    cvt2(T[wr4+2][wcol],h2,l2); cvt2(T[wr4+3][wcol],h3,l3);
    ushort4 hv = {h0,h1,h2,h3}, lv = {l0,l1,l2,l3};
    *(ushort4*)(h + (long)(c0 + wcol) * ldD + r0 + wr4) = hv;
    *(ushort4*)(l + (long)(c0 + wcol) * ldD + r0 + wr4) = lv;
}

// ---- fp32 transpose: dst[c][r] = src[r][c], 32x32 tiles ----
__global__ void utrans_kernel(const float* __restrict__ src, int ldS, long sS,
                              float* __restrict__ dst, int ldD, long sD) {
    int b = blockIdx.z;
    src += (long)b * sS; dst += (long)b * sD;
    __shared__ float T[32][33];
    int r0 = blockIdx.y * 32, c0 = blockIdx.x * 32;
    int tid = threadIdx.x;
    int lrow = tid >> 3, lc4 = (tid & 7) * 4;
    float4 v = *(const float4*)(src + (long)(r0 + lrow) * ldS + c0 + lc4);
    T[lrow][lc4+0]=v.x; T[lrow][lc4+1]=v.y; T[lrow][lc4+2]=v.z; T[lrow][lc4+3]=v.w;
    __syncthreads();
    int wcol = tid >> 3, wr4 = (tid & 7) * 4;
    float4 o;
    o.x = T[wr4+0][wcol]; o.y = T[wr4+1][wcol]; o.z = T[wr4+2][wcol]; o.w = T[wr4+3][wcol];
    *(float4*)(dst + (long)(c0 + wcol) * ldD + r0 + wr4) = o;
}

// ---------------- batched blocked Cholesky (BK=16, 1024 threads) ----------------

__global__ __launch_bounds__(1024) void chol_kernel(float* bufA, float* bufB) {
    int blk = blockIdx.x;                       // 0..31
    float* Ag = (blk < S_) ? (bufA + (long)blk * MM_) : (bufB + (long)(blk - S_) * MM_);
    __shared__ float P[33280];
    __shared__ float panT[16][256];
    __shared__ float piv[16][18];
    float4* P4 = (float4*)P;
    int tid = threadIdx.x;
    int r = tid >> 2, s = tid & 3;
    int lane = tid & 63, wid = tid >> 6;
    int mg = r >> 2, tg = r & 3;
    int b4 = (mg + 1) * (2 * mg + tg);

    for (int i = wid; i < M_; i += 16) {
        int m = i >> 2, t4 = i & 3;
        int rb4 = (m + 1) * (2 * m + t4);
        if (lane <= m) P4[rb4 + lane] = ((const float4*)Ag)[i * 64 + lane];
    }
    __syncthreads();

    float preg[16];
    for (int p = 0; p < 16; p++) {
        int k0 = p << 4;
        int c0 = p << 2;
        #pragma unroll
        for (int rr = 0; rr < 4; rr++) {
            float4 v = make_float4(0.f, 0.f, 0.f, 0.f);
            if (r >= k0 && c0 + rr <= mg) v = P4[b4 + c0 + rr];
            preg[4 * rr + 0] = v.x; preg[4 * rr + 1] = v.y;
            preg[4 * rr + 2] = v.z; preg[4 * rr + 3] = v.w;
        }
        if (wid == p) {
            int dj = lane >> 2;
            float myinv = 0.f;
            #pragma unroll
            for (int j = 0; j < 16; j++) {
                float app = __shfl(preg[j], 4 * j, 64);
                float d = sqrtf(app);
                float inv = 1.0f / d;
                if (dj == j) { preg[j] = d; myinv = inv; }
                else if (dj > j) preg[j] *= inv;
                #pragma unroll
                for (int j2 = j + 1; j2 < 16; j2++) {
                    float Lj2 = __shfl(preg[j], 4 * j2, 64);
                    if (dj >= j2) preg[j2] -= preg[j] * Lj2;
                }
            }
            if (s == 0) {
                #pragma unroll
                for (int i = 0; i < 16; i++) piv[dj][i] = preg[i];
                piv[dj][16] = myinv;
            }
        }
        __syncthreads();
        if (r > k0 + 15) {
            float x[16];
            #pragma unroll
            for (int j = 0; j < 16; j++) {
                float acc = preg[j];
                #pragma unroll
                for (int i = 0; i < 16; i++)
                    if (i < j) acc -= x[i] * piv[j][i];
                x[j] = acc * piv[j][16];
            }
            #pragma unroll
            for (int j = 0; j < 16; j++) preg[j] = x[j];
        }
        if (r >= k0) {
            #pragma unroll
            for (int j = 0; j < 4; j++) panT[4 * s + j][r] = preg[4 * s + j];
            int c = c0 + s;
            if (c <= mg)
                P4[b4 + c] = make_float4(preg[4 * s], preg[4 * s + 1],
                                         preg[4 * s + 2], preg[4 * s + 3]);
        }
        __syncthreads();
        if (r > k0 + 15) {
            for (int c = c0 + 4 + s; c <= mg; c += 4) {
                float4 rv = P4[b4 + c];
                #pragma unroll
                for (int tt = 0; tt < 16; tt++) {
                    float4 pv = *(const float4*)&panT[tt][c << 2];
                    rv.x -= preg[tt] * pv.x;
                    rv.y -= preg[tt] * pv.y;
                    rv.z -= preg[tt] * pv.z;
                    rv.w -= preg[tt] * pv.w;
                }
                P4[b4 + c] = rv;
            }
        }
        __syncthreads();
    }

    for (int i = wid; i < M_; i += 16) {
        int m = i >> 2, t4 = i & 3;
        int rb4 = (m + 1) * (2 * m + t4);
        if (lane <= m) ((float4*)Ag)[i * 64 + lane] = P4[rb4 + lane];
    }
}

// ---------------- batched blocked triangular inverse (BK=16) ----------------
// Writes the TRANSPOSED inverse directly as bf16 hi/lo pairs: Tt[j][k] = T[k][j].

__global__ __launch_bounds__(256) void trinv_kernel(const float* bufA, const float* bufB,
                                                    u16* TKth, u16* TKtl,
                                                    u16* Tlth, u16* Tltl) {
    int mat = blockIdx.y;      // 0..31
    int cb  = blockIdx.x;      // 0..3
    const float* Lg = (mat < S_) ? (bufA + (long)mat * MM_) : (bufB + (long)(mat - S_) * MM_);
    u16* dh; u16* dl; long mb;
    if (mat < S_) { dh = TKth; dl = TKtl; mb = (long)mat * MM_; }
    else          { dh = Tlth; dl = Tltl; mb = (long)(mat - S_) * MM_; }
    __shared__ float X[M_ * 65];
    __shared__ float panR[M_ * 20];
    int tid = threadIdx.x;
    int c = tid & 63, q = tid >> 6;
    int jglob = cb * 64 + c;

    for (int idx = tid; idx < M_ * 65; idx += 256) X[idx] = 0.f;
    __syncthreads();
    if (q == 0) X[jglob * 65 + c] = 1.0f;

    int p0 = cb * 4;
    for (int p = p0; p < 16; p++) {
        int t0 = p << 4;
        int k = t0 + tid;
        if (k < M_) {
            const float4* src = (const float4*)&Lg[(long)k * M_ + t0];
            float4* dst = (float4*)&panR[k * 20];
            dst[0] = src[0]; dst[1] = src[1]; dst[2] = src[2]; dst[3] = src[3];
        }
        __syncthreads();
        if (q == (t0 >> 6)) {
            float xr[16];
            #pragma unroll
            for (int j = 0; j < 16; j++) {
                float xv = X[(t0 + j) * 65 + c];
                #pragma unroll
                for (int i = 0; i < 16; i++)
                    if (i < j) xv -= panR[(t0 + j) * 20 + i] * xr[i];
                xv *= (1.0f / panR[(t0 + j) * 20 + j]);
                xr[j] = xv;
                X[(t0 + j) * 65 + c] = xv;
            }
        }
        __syncthreads();
        int kbeg = q << 6; if (kbeg < t0 + 16) kbeg = t0 + 16;
        int kend = (q << 6) + 64;
        if (kbeg < kend) {
            float xr[16];
            #pragma unroll
            for (int j = 0; j < 16; j++) xr[j] = X[(t0 + j) * 65 + c];
            for (int kk = kbeg; kk < kend; kk++) {
                float rv = X[kk * 65 + c];
                const float4* pr = (const float4*)&panR[kk * 20];
                float4 a = pr[0], b = pr[1], d = pr[2], e = pr[3];
                rv -= a.x * xr[0] + a.y * xr[1] + a.z * xr[2] + a.w * xr[3];
                rv -= b.x * xr[4] + b.y * xr[5] + b.z * xr[6] + b.w * xr[7];
                rv -= d.x * xr[8] + d.y * xr[9] + d.z * xr[10] + d.w * xr[11];
                rv -= e.x * xr[12] + e.y * xr[13] + e.z * xr[14] + e.w * xr[15];
                X[kk * 65 + c] = rv;
            }
        }
        __syncthreads();
    }

    // writeback transposed pair: Tt[jglob][k] = X[k][c]
    for (int idx = tid; idx < 64 * 256; idx += 256) {
        int k = idx & 255, cc = idx >> 8;
        float val = X[k * 65 + cc];
        u16 h, l; cvt2(val, h, l);
        long o = mb + (long)(cb * 64 + cc) * 256 + k;
        dh[o] = h; dl[o] = l;
    }
}

// ---------------- pair GEMM: C = alpha * A @ B^T(storage) + epilogue ----------------
// A pair storage [i][k] (TA0), B pair storage [j][k] (TB1). K = 256 always.
// M, N multiples of 128. 3 MFMAs per fragment pair (hh + hl + lh).

struct PG {
    const u16 *Ah, *Al, *Bh, *Bl;
    float* C; u16 *Ch, *Cl, *ChT, *ClT;
    const float* D; const float* vfp; const float* noise;
    int M, N, lda, ldb, ldc, ldct;
    long sA, sB, sC, sP, sCt, sD, sVf, sNoise;
    float alpha, dcoef;
};

template<int OF, int OP, int OPT, int ACCf, int Df, int ADDIf, int EFf>
__global__ __launch_bounds__(256) void pgemm_k(PG p) {
    int bz = blockIdx.z;
    const u16* Agh = p.Ah + (long)bz * p.sA;
    const u16* Agl = p.Al + (long)bz * p.sA;
    const u16* Bgh = p.Bh + (long)bz * p.sB;
    const u16* Bgl = p.Bl + (long)bz * p.sB;
    int bm = blockIdx.y * 128, bn = blockIdx.x * 128;
    __shared__ __align__(16) u16 sAh[128][40];
    __shared__ __align__(16) u16 sAl[128][40];
    __shared__ __align__(16) u16 sBh[128][40];
    __shared__ __align__(16) u16 sBl[128][40];
    int tid = threadIdx.x, lane = tid & 63, wid = tid >> 6;
    int wm = (wid >> 1) * 64, wn = (wid & 1) * 64;
    int fr = lane & 15, ko = (lane >> 4) * 8;
    int kb = tid & 3, rw = tid >> 2;           // staging coords
    f32x4 acc[4][4];
    #pragma unroll
    for (int m = 0; m < 4; m++)
        #pragma unroll
        for (int n = 0; n < 4; n++)
            acc[m][n] = (f32x4){0.f, 0.f, 0.f, 0.f};

    for (int k0 = 0; k0 < 256; k0 += 32) {
        #define STG(SRC, LD, BASE, DST) \
            *(bf16x8*)&DST[rw][kb * 8] = \
                *(const bf16x8*)(SRC + (long)(BASE + rw) * LD + k0 + kb * 8); \
            *(bf16x8*)&DST[rw + 64][kb * 8] = \
                *(const bf16x8*)(SRC + (long)(BASE + rw + 64) * LD + k0 + kb * 8);
        STG(Agh, p.lda, bm, sAh)
        STG(Agl, p.lda, bm, sAl)
        STG(Bgh, p.ldb, bn, sBh)
        STG(Bgl, p.ldb, bn, sBl)
        #undef STG
        __syncthreads();
        bf16x8 ah[4], al[4], bh[4], bl[4];
        #pragma unroll
        for (int m = 0; m < 4; m++) {
            ah[m] = *(const bf16x8*)&sAh[wm + m * 16 + fr][ko];
            al[m] = *(const bf16x8*)&sAl[wm + m * 16 + fr][ko];
        }
        #pragma unroll
        for (int n = 0; n < 4; n++) {
            bh[n] = *(const bf16x8*)&sBh[wn + n * 16 + fr][ko];
            bl[n] = *(const bf16x8*)&sBl[wn + n * 16 + fr][ko];
        }
        #pragma unroll
        for (int m = 0; m < 4; m++)
            #pragma unroll
            for (int n = 0; n < 4; n++) {
                acc[m][n] = __builtin_amdgcn_mfma_f32_16x16x32_bf16(ah[m], bh[n], acc[m][n], 0, 0, 0);
                acc[m][n] = __builtin_amdgcn_mfma_f32_16x16x32_bf16(ah[m], bl[n], acc[m][n], 0, 0, 0);
                acc[m][n] = __builtin_amdgcn_mfma_f32_16x16x32_bf16(al[m], bh[n], acc[m][n], 0, 0, 0);
            }
        __syncthreads();
    }

    int rq = (lane >> 4) * 4;
    #pragma unroll
    for (int m = 0; m < 4; m++) {
        int row0 = bm + wm + m * 16 + rq;
        #pragma unroll
        for (int n = 0; n < 4; n++) {
            int col = bn + wn + n * 16 + fr;
            float v[4];
            #pragma unroll
            for (int i = 0; i < 4; i++) {
                int r = row0 + i;
                float val = p.alpha * acc[m][n][i];
                if (Df)   val += p.dcoef * p.D[(long)bz * p.sD + (long)r * p.ldc + col];
                if (ACCf) val += p.C[(long)bz * p.sC + (long)r * p.ldc + col];
                if (ADDIf && r == col) val += 1.0f;
                if (EFf)  val += p.vfp[(long)bz * p.sVf + r] *
                                 p.noise[(long)bz * p.sNoise + (long)r * 256 + col];
                v[i] = val;
            }
            if (OF) {
                #pragma unroll
                for (int i = 0; i < 4; i++)
                    p.C[(long)bz * p.sC + (long)(row0 + i) * p.ldc + col] = v[i];
            }
            if (OP) {
                #pragma unroll
                for (int i = 0; i < 4; i++) {
                    u16 h, l; cvt2(v[i], h, l);
                    p.Ch[(long)bz * p.sP + (long)(row0 + i) * p.ldc + col] = h;
                    p.Cl[(long)bz * p.sP + (long)(row0 + i) * p.ldc + col] = l;
                }
            }
            if (OPT) {
                u16 h0,h1,h2,h3,l0,l1,l2,l3;
                cvt2(v[0],h0,l0); cvt2(v[1],h1,l1); cvt2(v[2],h2,l2); cvt2(v[3],h3,l3);
                ushort4 hv = {h0,h1,h2,h3}, lv = {l0,l1,l2,l3};
                *(ushort4*)&p.ChT[(long)bz * p.sCt + (long)col * p.ldct + row0] = hv;
                *(ushort4*)&p.ClT[(long)bz * p.sCt + (long)col * p.ldct + row0] = lv;
            }
        }
    }
}

// ---------------- Vf = sqrt(Kff - sum_m AchT*KufT), both [f][m]-major pairs ----------------

__global__ void vf_kernel(const u16* __restrict__ Ah, const u16* __restrict__ Al,
                          const u16* __restrict__ Kh, const u16* __restrict__ Kl,
                          const float* __restrict__ Kff, float* __restrict__ Vf,
                          int f0, int w) {
    int s = blockIdx.y;
    int fl = blockIdx.x * 64 + (threadIdx.x >> 2);
    int mq = threadIdx.x & 3;
    long base = ((long)s * w + fl) * 256;
    float acc = 0.f;
    for (int it = 0; it < 8; it++) {
        int mb = it * 32 + mq * 8;
        bf16x8 a_h = *(const bf16x8*)(Ah + base + mb);
        bf16x8 a_l = *(const bf16x8*)(Al + base + mb);
        bf16x8 k_h = *(const bf16x8*)(Kh + base + mb);
        bf16x8 k_l = *(const bf16x8*)(Kl + base + mb);
        #pragma unroll
        for (int e = 0; e < 8; e++) {
            float a = bfa((u16)a_h[e]) + bfa((u16)a_l[e]);
            float b = bfa((u16)k_h[e]) + bfa((u16)k_l[e]);
            acc += a * b;
        }
    }
    acc += __shfl_xor(acc, 1);
    acc += __shfl_xor(acc, 2);
    if (mq == 0) {
        float v = Kff[(long)s * NF_ + f0 + fl] - acc;
        Vf[(long)s * NF_ + f0 + fl] = sqrtf(fmaxf(v, 0.f));
    }
}

// ---------------- host ----------------

extern "C" void kernel_launch(void* const* d_in, const int* in_sizes, int n_in,
                              void* d_out, int out_size, void* d_ws, size_t ws_size,
                              hipStream_t stream) {
    const float* Kuu       = (const float*)d_in[0];
    const float* Kuf       = (const float*)d_in[1];
    const float* Kff       = (const float*)d_in[2];
    const float* Lloc      = (const float*)d_in[3];
    const float* Lscale    = (const float*)d_in[4];
    const float* u_param   = (const float*)d_in[5];
    const float* noise_inv = (const float*)d_in[6];
    const float* noise_L   = (const float*)d_in[7];
    const float* noise_f   = (const float*)d_in[8];
    float* out = (float*)d_out;
    float* ws  = (float*)d_ws;

    const long BIG = (long)S_ * MM_;     // 1,048,576 elements
    long off = 1024;
    float* part = ws + 16;

    // pair buffer: h (E u16) + l (E u16) = E floats total
    #define PAIR(NAME, E) u16* NAME##h = (u16*)(ws + off); u16* NAME##l = NAME##h + (E); off += (E);
    PAIR(LS, 65536)          // L (scaled)            [m][m']
    PAIR(LtS, 65536)         // L^T                   [m'][m]
    PAIR(upS, 65536)         // u_param               [o][m]
    PAIR(W1S, 65536)         // up @ L                [o][m']
    float* UPT = ws + off; off += 65536;   // (L L^T u^T)^T fp32  [o][m]
    float* Vf  = ws + off; off += 65536;
    PAIR(KuuS, BIG)          // slot A: later RHST pair
    PAIR(ninvS, BIG)         // slot B
    PAIR(nLS, BIG)           // slot C: later UT pair
    float* cholK = ws + off; off += BIG;   // slot D: later KuuInv pair
    PAIR(KuuLS, BIG)         // slot E: later RHS1T fp32
    PAIR(KuuLtS, BIG)        // slot F: later Sigma pair
    float* choll = ws + off; off += BIG;   // slot G: later lKlpIi pair
    PAIR(TKtS, BIG)          // slot H: later UT fp32
    PAIR(TltS, BIG)          // slot I: later Stmp pair
    #undef PAIR

    // aliases (lifetime-disjoint reuse)
    u16* RHSTh   = KuuSh;            u16* RHSTl   = KuuSl;
    u16* UTph    = nLSh;             u16* UTpl    = nLSl;
    u16* KuuInvh = (u16*)cholK;      u16* KuuInvl = KuuInvh + BIG;
    float* RHS1T = (float*)KuuLSh;
    u16* Sigmah  = KuuLtSh;          u16* Sigmal  = KuuLtSl;
    u16* lKlh    = (u16*)choll;      u16* lKll    = lKlh + BIG;
    float* UTf32 = (float*)TKtSh;
    u16* Stmph   = TltSh;            u16* Stmpl   = TltSl;

    // chunk buffers
    long navail = (long)(ws_size / 4) - off;
    long nfc_l = navail / 8192;               // floats per f-col for 2 pair buffers
    int nfc = (int)((nfc_l / 128) * 128);
    if (nfc > NF_) nfc = NF_;
    if (nfc < 128) nfc = 128;
    long Ec = (long)S_ * nfc * 256;
    u16* KufTch = (u16*)(ws + off);  u16* KufTcl = KufTch + Ec;
    u16* AchTch = (u16*)(ws + off + Ec); u16* AchTcl = AchTch + Ec;

    dim3 b256(256);

    // scalars
    max1_kernel<<<256, b256, 0, stream>>>(Kuu, S_ * MM_, part);
    max2_kernel<<<1, b256, 0, stream>>>(part, ws);
    prep_kernel<<<1, b256, 0, stream>>>(Lloc, Lscale, ws);

    // splits
    psplit_kernel<<<1024, b256, 0, stream>>>(Kuu, KuuSh, KuuSl, BIG, nullptr);
    psplit_kernel<<<64, b256, 0, stream>>>(Lloc, LSh, LSl, 65536, ws + 1);
    tsplit_kernel<<<dim3(8, 8, 1), b256, 0, stream>>>(Lloc, 256, 0, LtSh, LtSl, 256, 0, ws + 1);
    psplit_kernel<<<64, b256, 0, stream>>>(u_param, upSh, upSl, 65536, nullptr);
    psplit_kernel<<<1024, b256, 0, stream>>>(noise_inv, ninvSh, ninvSl, BIG, nullptr);
    psplit_kernel<<<1024, b256, 0, stream>>>(noise_L, nLSh, nLSl, BIG, nullptr);
    copyjit_kernel<<<4096, b256, 0, stream>>>(Kuu, ws, cholK);

    PG q;
    auto clr = [&]() {
        q = PG{};
        q.lda = 256; q.ldb = 256; q.ldc = 256; q.ldct = 256;
        q.alpha = 1.f; q.dcoef = 1.f;
        q.M = 256; q.N = 256;
    };

    // a. KuuL = Kuu @ L  -> pair + pairT
    clr(); q.Ah = KuuSh; q.Al = KuuSl; q.sA = MM_;
    q.Bh = LtSh; q.Bl = LtSl; q.sB = 0;
    q.Ch = KuuLSh; q.Cl = KuuLSl; q.sP = MM_;
    q.ChT = KuuLtSh; q.ClT = KuuLtSl; q.sCt = MM_;
    pgemm_k<0,1,1,0,0,0,0><<<dim3(2, 2, S_), b256, 0, stream>>>(q);

    // b. choll = KuuL^T @ L + I  (= L^T Kuu L + I, symmetric) -> fp32
    clr(); q.Ah = KuuLtSh; q.Al = KuuLtSl; q.sA = MM_;
    q.Bh = LtSh; q.Bl = LtSl; q.sB = 0;
    q.C = choll; q.sC = MM_;
    pgemm_k<1,0,0,0,0,1,0><<<dim3(2, 2, S_), b256, 0, stream>>>(q);

    chol_kernel<<<32, dim3(1024), 0, stream>>>(cholK, choll);
    trinv_kernel<<<dim3(4, 32), b256, 0, stream>>>(cholK, choll, TKtSh, TKtSl, TltSh, TltSl);

    // c. KuuInv = TKt @ TKt^T -> pair
    clr(); q.Ah = TKtSh; q.Al = TKtSl; q.sA = MM_;
    q.Bh = TKtSh; q.Bl = TKtSl; q.sB = MM_;
    q.Ch = KuuInvh; q.Cl = KuuInvl; q.sP = MM_;
    pgemm_k<0,1,0,0,0,0,0><<<dim3(2, 2, S_), b256, 0, stream>>>(q);

    // d. lKlpIi = Tlt @ Tlt^T -> pair
    clr(); q.Ah = TltSh; q.Al = TltSl; q.sA = MM_;
    q.Bh = TltSh; q.Bl = TltSl; q.sB = MM_;
    q.Ch = lKlh; q.Cl = lKll; q.sP = MM_;
    pgemm_k<0,1,0,0,0,0,0><<<dim3(2, 2, S_), b256, 0, stream>>>(q);

    // e. Stmp = KuuL @ lKlpIi (B symmetric) -> pair
    clr(); q.Ah = KuuLSh; q.Al = KuuLSl; q.sA = MM_;
    q.Bh = lKlh; q.Bl = lKll; q.sB = MM_;
    q.Ch = Stmph; q.Cl = Stmpl; q.sP = MM_;
    pgemm_k<0,1,0,0,0,0,0><<<dim3(2, 2, S_), b256, 0, stream>>>(q);

    // f. Sigma = Kuu - Stmp @ KuuL^T -> pair
    clr(); q.Ah = Stmph; q.Al = Stmpl; q.sA = MM_;
    q.Bh = KuuLSh; q.Bl = KuuLSl; q.sB = MM_;
    q.Ch = Sigmah; q.Cl = Sigmal; q.sP = MM_;
    q.D = Kuu; q.sD = MM_; q.alpha = -1.f;
    pgemm_k<0,1,0,0,1,0,0><<<dim3(2, 2, S_), b256, 0, stream>>>(q);

    // g. W1 = up @ L -> pair (batch 1)
    clr(); q.Ah = upSh; q.Al = upSl; q.sA = 0;
    q.Bh = LtSh; q.Bl = LtSl; q.sB = 0;
    q.Ch = W1Sh; q.Cl = W1Sl; q.sP = 0;
    pgemm_k<0,1,0,0,0,0,0><<<dim3(2, 2, 1), b256, 0, stream>>>(q);

    // h. UPT = W1 @ L^T -> fp32 (batch 1)
    clr(); q.Ah = W1Sh; q.Al = W1Sl; q.sA = 0;
    q.Bh = LSh; q.Bl = LSl; q.sB = 0;
    q.C = UPT; q.sC = 0;
    pgemm_k<1,0,0,0,0,0,0><<<dim3(2, 2, 1), b256, 0, stream>>>(q);

    // i. RHS1T = ninv @ TK + UPT -> fp32
    clr(); q.Ah = ninvSh; q.Al = ninvSl; q.sA = 65536;
    q.Bh = TKtSh; q.Bl = TKtSl; q.sB = MM_;
    q.C = RHS1T; q.sC = MM_;
    q.D = UPT; q.sD = 0;
    pgemm_k<1,0,0,0,1,0,0><<<dim3(2, 2, S_), b256, 0, stream>>>(q);

    // j. RHST = nL @ L^T + RHS1T -> pair
    clr(); q.Ah = nLSh; q.Al = nLSl; q.sA = 65536;
    q.Bh = LSh; q.Bl = LSl; q.sB = 0;
    q.C = RHS1T; q.sC = MM_;
    q.Ch = RHSTh; q.Cl = RHSTl; q.sP = MM_;
    pgemm_k<0,1,0,1,0,0,0><<<dim3(2, 2, S_), b256, 0, stream>>>(q);

    // k. UT = RHST @ Sigma (B symmetric) -> fp32 + pair
    clr(); q.Ah = RHSTh; q.Al = RHSTl; q.sA = MM_;
    q.Bh = Sigmah; q.Bl = Sigmal; q.sB = MM_;
    q.C = UTf32; q.sC = MM_;
    q.Ch = UTph; q.Cl = UTpl; q.sP = MM_;
    pgemm_k<1,1,0,0,0,0,0><<<dim3(2, 2, S_), b256, 0, stream>>>(q);

    // out rows 0..255: out[s][m][o] = UT[s][o][m]
    utrans_kernel<<<dim3(8, 8, S_), b256, 0, stream>>>(UTf32, 256, MM_, out, OUT_, (long)ROWS_ * OUT_);

    for (int f0 = 0; f0 < NF_; f0 += nfc) {
        int w = NF_ - f0; if (w > nfc) w = nfc;
        // KufT chunk: [s][f][m] pair  (transpose-split of Kuf[:, f0:f0+w])
        tsplit_kernel<<<dim3(w / 32, 8, S_), b256, 0, stream>>>(
            Kuf + f0, NF_, (long)M_ * NF_, KufTch, KufTcl, 256, (long)w * 256, nullptr);
        // l. AchT = KufT @ KuuInv (B symmetric) -> pair
        clr(); q.M = w; q.N = 256;
        q.Ah = KufTch; q.Al = KufTcl; q.sA = (long)w * 256;
        q.Bh = KuuInvh; q.Bl = KuuInvl; q.sB = MM_;
        q.Ch = AchTch; q.Cl = AchTcl; q.sP = (long)w * 256;
        pgemm_k<0,1,0,0,0,0,0><<<dim3(2, w / 128, S_), b256, 0, stream>>>(q);
        // Vf
        vf_kernel<<<dim3(w / 64, S_), b256, 0, stream>>>(
            AchTch, AchTcl, KufTch, KufTcl, Kff, Vf, f0, w);
        // m. out_f = AchT @ UT^T + sqrt(Vf)*noise_f -> fp32 into out
        clr(); q.M = w; q.N = 256;
        q.Ah = AchTch; q.Al = AchTcl; q.sA = (long)w * 256;
        q.Bh = UTph; q.Bl = UTpl; q.sB = MM_;
        q.C = out + (long)(M_ + f0) * OUT_; q.sC = (long)ROWS_ * OUT_;
        q.vfp = Vf + f0; q.sVf = NF_;
        q.noise = noise_f + (long)f0 * OUT_; q.sNoise = (long)NF_ * OUT_;
        pgemm_k<1,0,0,0,0,0,1><<<dim3(2, w / 128, S_), b256, 0, stream>>>(q);
    }
}

// Round 8
// 605.358 us; speedup vs baseline: 1.3678x; 1.0060x over previous
//
#include <hip/hip_runtime.h>
#include <math.h>

#define S_ 16
#define M_ 256
#define NF_ 4096
#define OUT_ 256
#define ROWS_ (M_ + NF_)     // 4352
#define JITTER_ 1e-8f
#define MM_ (M_ * M_)        // 65536

typedef unsigned short u16;
typedef __attribute__((ext_vector_type(8))) short bf16x8;
typedef __attribute__((ext_vector_type(4))) float f32x4;

__device__ inline void cvt2(float x, u16& h, u16& l) {
    unsigned xb = __float_as_uint(x);
    unsigned hb = (xb + 0x7fffu + ((xb >> 16) & 1u)) >> 16;
    float fh = __uint_as_float(hb << 16);
    float rr = x - fh;
    unsigned rb = __float_as_uint(rr);
    unsigned lb = (rb + 0x7fffu + ((rb >> 16) & 1u)) >> 16;
    h = (u16)hb; l = (u16)lb;
}

// ---------------- small prep kernels ----------------

__global__ void max1_kernel(const float* __restrict__ x, int n, float* part) {
    __shared__ float red[256];
    int tid = threadIdx.x;
    float m = -3.4e38f;
    for (int i = blockIdx.x * blockDim.x + tid; i < n; i += gridDim.x * blockDim.x)
        m = fmaxf(m, x[i]);
    red[tid] = m; __syncthreads();
    for (int s = 128; s > 0; s >>= 1) {
        if (tid < s) red[tid] = fmaxf(red[tid], red[tid + s]);
        __syncthreads();
    }
    if (tid == 0) part[blockIdx.x] = red[0];
}

__global__ void max2_kernel(const float* part, float* ws) {
    __shared__ float red[256];
    int tid = threadIdx.x;
    red[tid] = part[tid]; __syncthreads();
    for (int s = 128; s > 0; s >>= 1) {
        if (tid < s) red[tid] = fmaxf(red[tid], red[tid + s]);
        __syncthreads();
    }
    if (tid == 0) { ws[0] = red[0]; ws[2] = JITTER_ * red[0]; }
}

__global__ void prep_kernel(const float* __restrict__ Lloc, const float* __restrict__ Lscale, float* ws) {
    __shared__ float red[256];
    int tid = threadIdx.x;
    red[tid] = Lloc[tid * M_ + tid];
    __syncthreads();
    for (int s = 128; s > 0; s >>= 1) {
        if (tid < s) red[tid] += red[tid + s];
        __syncthreads();
    }
    if (tid == 0) {
        float norm = red[0] / (float)M_;
        ws[1] = expf(Lscale[0]) / norm;
    }
}

__global__ void copyjit_kernel(const float* __restrict__ Kuu, const float* __restrict__ ws, float* __restrict__ dst) {
    int i = blockIdx.x * blockDim.x + threadIdx.x;
    if (i < S_ * MM_) {
        float v = Kuu[i];
        int r = (i >> 8) & 255;
        int c = i & 255;
        if (r == c) v += ws[2];
        dst[i] = v;
    }
}

// ---- plain split: fp32 -> bf16 hi/lo (optional scale from device ptr) ----
__global__ void psplit_kernel(const float* __restrict__ src, u16* __restrict__ h,
                              u16* __restrict__ l, long n, const float* scaleptr) {
    float sc = scaleptr ? scaleptr[0] : 1.0f;
    long stride = (long)gridDim.x * blockDim.x * 4;
    for (long i = ((long)blockIdx.x * blockDim.x + threadIdx.x) * 4; i < n; i += stride) {
        float4 v = *(const float4*)(src + i);
        u16 h0,h1,h2,h3,l0,l1,l2,l3;
        cvt2(v.x*sc,h0,l0); cvt2(v.y*sc,h1,l1); cvt2(v.z*sc,h2,l2); cvt2(v.w*sc,h3,l3);
        ushort4 hv = {h0,h1,h2,h3}, lv = {l0,l1,l2,l3};
        *(ushort4*)(h + i) = hv;
        *(ushort4*)(l + i) = lv;
    }
}

// ---- transpose split: src[r][c] (ldS) -> dst[c][r] (ldD) bf16 hi/lo ----
__global__ void tsplit_kernel(const float* __restrict__ src, int ldS, long sS,
                              u16* __restrict__ h, u16* __restrict__ l, int ldD, long sD,
                              const float* scaleptr) {
    int b = blockIdx.z;
    src += (long)b * sS; h += (long)b * sD; l += (long)b * sD;
    __shared__ float T[32][33];
    int r0 = blockIdx.y * 32, c0 = blockIdx.x * 32;
    float sc = scaleptr ? scaleptr[0] : 1.0f;
    int tid = threadIdx.x;
    int lrow = tid >> 3, lc4 = (tid & 7) * 4;
    float4 v = *(const float4*)(src + (long)(r0 + lrow) * ldS + c0 + lc4);
    T[lrow][lc4 + 0] = v.x * sc; T[lrow][lc4 + 1] = v.y * sc;
    T[lrow][lc4 + 2] = v.z * sc; T[lrow][lc4 + 3] = v.w * sc;
    __syncthreads();
    int wcol = tid >> 3, wr4 = (tid & 7) * 4;
    u16 h0,h1,h2,h3,l0,l1,l2,l3;
    cvt2(T[wr4+0][wcol],h0,l0); cvt2(T[wr4+1][wcol],h1,l1);
    cvt2(T[wr4+2][wcol],h2,l2); cvt2(T[wr4+3][wcol],h3,l3);
    ushort4 hv = {h0,h1,h2,h3}, lv = {l0,l1,l2,l3};
    *(ushort4*)(h + (long)(c0 + wcol) * ldD + r0 + wr4) = hv;
    *(ushort4*)(l + (long)(c0 + wcol) * ldD + r0 + wr4) = lv;
}

// ---- fp32 transpose: dst[c][r] = src[r][c], 32x32 tiles ----
__global__ void utrans_kernel(const float* __restrict__ src, int ldS, long sS,
                              float* __restrict__ dst, int ldD, long sD) {
    int b = blockIdx.z;
    src += (long)b * sS; dst += (long)b * sD;
    __shared__ float T[32][33];
    int r0 = blockIdx.y * 32, c0 = blockIdx.x * 32;
    int tid = threadIdx.x;
    int lrow = tid >> 3, lc4 = (tid & 7) * 4;
    float4 v = *(const float4*)(src + (long)(r0 + lrow) * ldS + c0 + lc4);
    T[lrow][lc4+0]=v.x; T[lrow][lc4+1]=v.y; T[lrow][lc4+2]=v.z; T[lrow][lc4+3]=v.w;
    __syncthreads();
    int wcol = tid >> 3, wr4 = (tid & 7) * 4;
    float4 o;
    o.x = T[wr4+0][wcol]; o.y = T[wr4+1][wcol]; o.z = T[wr4+2][wcol]; o.w = T[wr4+3][wcol];
    *(float4*)(dst + (long)(c0 + wcol) * ldD + r0 + wr4) = o;
}

// ---------------- batched blocked Cholesky (BK=16, 1024 threads) ----------------
// Panel published ROW-major: pan2[r][j] = L[r][k0+j], stride 20 floats so each
// sub's float4 write is clean and (D)'s reads are 4-distinct-address b128.

__global__ __launch_bounds__(1024) void chol_kernel(float* bufA, float* bufB) {
    int blk = blockIdx.x;                       // 0..31
    float* Ag = (blk < S_) ? (bufA + (long)blk * MM_) : (bufB + (long)(blk - S_) * MM_);
    __shared__ float P[33280];                  // 133120 B
    __shared__ float pan2[256 * 20];            // 20480 B  [row][panel col]
    __shared__ float piv[16][18];
    float4* P4 = (float4*)P;
    int tid = threadIdx.x;
    int r = tid >> 2, s = tid & 3;
    int lane = tid & 63, wid = tid >> 6;        // wave w holds rows 16w..16w+15
    int mg = r >> 2, tg = r & 3;
    int b4 = (mg + 1) * (2 * mg + tg);

    for (int i = wid; i < M_; i += 16) {
        int m = i >> 2, t4 = i & 3;
        int rb4 = (m + 1) * (2 * m + t4);
        if (lane <= m) P4[rb4 + lane] = ((const float4*)Ag)[i * 64 + lane];
    }
    __syncthreads();

    float preg[16];
    for (int p = 0; p < 16; p++) {
        int k0 = p << 4;
        int c0 = p << 2;
        #pragma unroll
        for (int rr = 0; rr < 4; rr++) {
            float4 v = make_float4(0.f, 0.f, 0.f, 0.f);
            if (r >= k0 && c0 + rr <= mg) v = P4[b4 + c0 + rr];
            preg[4 * rr + 0] = v.x; preg[4 * rr + 1] = v.y;
            preg[4 * rr + 2] = v.z; preg[4 * rr + 3] = v.w;
        }
        if (wid == p) {
            int dj = lane >> 2;
            float myinv = 0.f;
            #pragma unroll
            for (int j = 0; j < 16; j++) {
                float app = __shfl(preg[j], 4 * j, 64);
                float d = sqrtf(app);
                float inv = 1.0f / d;
                if (dj == j) { preg[j] = d; myinv = inv; }
                else if (dj > j) preg[j] *= inv;
                #pragma unroll
                for (int j2 = j + 1; j2 < 16; j2++) {
                    float Lj2 = __shfl(preg[j], 4 * j2, 64);
                    if (dj >= j2) preg[j2] -= preg[j] * Lj2;
                }
            }
            if (s == 0) {
                #pragma unroll
                for (int i = 0; i < 16; i++) piv[dj][i] = preg[i];
                piv[dj][16] = myinv;
            }
        }
        __syncthreads();
        if (r > k0 + 15) {
            float x[16];
            #pragma unroll
            for (int j = 0; j < 16; j++) {
                float acc = preg[j];
                #pragma unroll
                for (int i = 0; i < 16; i++)
                    if (i < j) acc -= x[i] * piv[j][i];
                x[j] = acc * piv[j][16];
            }
            #pragma unroll
            for (int j = 0; j < 16; j++) preg[j] = x[j];
        }
        if (r >= k0) {
            float4 pv = make_float4(preg[4 * s], preg[4 * s + 1],
                                    preg[4 * s + 2], preg[4 * s + 3]);
            *(float4*)&pan2[r * 20 + 4 * s] = pv;       // row-major publish
            int c = c0 + s;
            if (c <= mg) P4[b4 + c] = pv;
        }
        __syncthreads();
        if (r > k0 + 15) {
            for (int c = c0 + 4 + s; c <= mg; c += 4) {
                float rv[4];
                *(float4*)rv = P4[b4 + c];
                #pragma unroll
                for (int e = 0; e < 4; e++) {
                    const float4* pr = (const float4*)&pan2[(4 * c + e) * 20];
                    float4 q0 = pr[0], q1 = pr[1], q2 = pr[2], q3 = pr[3];
                    float a;
                    a  = preg[0]*q0.x + preg[1]*q0.y + preg[2]*q0.z + preg[3]*q0.w;
                    a += preg[4]*q1.x + preg[5]*q1.y + preg[6]*q1.z + preg[7]*q1.w;
                    a += preg[8]*q2.x + preg[9]*q2.y + preg[10]*q2.z + preg[11]*q2.w;
                    a += preg[12]*q3.x + preg[13]*q3.y + preg[14]*q3.z + preg[15]*q3.w;
                    rv[e] -= a;
                }
                P4[b4 + c] = *(float4*)rv;
            }
        }
        __syncthreads();
    }

    for (int i = wid; i < M_; i += 16) {
        int m = i >> 2, t4 = i & 3;
        int rb4 = (m + 1) * (2 * m + t4);
        if (lane <= m) ((float4*)Ag)[i * 64 + lane] = P4[rb4 + lane];
    }
}

// ---------------- batched blocked triangular inverse (BK=16) ----------------
// Emits transposed pair Tt[j][k]; for the Kuu set also row-major pair T[k][j].

__global__ __launch_bounds__(256) void trinv_kernel(const float* bufA, const float* bufB,
                                                    u16* TKth, u16* TKtl,
                                                    u16* Tlth, u16* Tltl,
                                                    u16* TKrh, u16* TKrl) {
    int mat = blockIdx.y;      // 0..31
    int cb  = blockIdx.x;      // 0..3
    const float* Lg = (mat < S_) ? (bufA + (long)mat * MM_) : (bufB + (long)(mat - S_) * MM_);
    u16* dh; u16* dl; long mb;
    if (mat < S_) { dh = TKth; dl = TKtl; mb = (long)mat * MM_; }
    else          { dh = Tlth; dl = Tltl; mb = (long)(mat - S_) * MM_; }
    __shared__ float X[M_ * 65];
    __shared__ float panR[M_ * 20];
    int tid = threadIdx.x;
    int c = tid & 63, q = tid >> 6;
    int jglob = cb * 64 + c;

    for (int idx = tid; idx < M_ * 65; idx += 256) X[idx] = 0.f;
    __syncthreads();
    if (q == 0) X[jglob * 65 + c] = 1.0f;

    int p0 = cb * 4;
    for (int p = p0; p < 16; p++) {
        int t0 = p << 4;
        int k = t0 + tid;
        if (k < M_) {
            const float4* src = (const float4*)&Lg[(long)k * M_ + t0];
            float4* dst = (float4*)&panR[k * 20];
            dst[0] = src[0]; dst[1] = src[1]; dst[2] = src[2]; dst[3] = src[3];
        }
        __syncthreads();
        if (q == (t0 >> 6)) {
            float xr[16];
            #pragma unroll
            for (int j = 0; j < 16; j++) {
                float xv = X[(t0 + j) * 65 + c];
                #pragma unroll
                for (int i = 0; i < 16; i++)
                    if (i < j) xv -= panR[(t0 + j) * 20 + i] * xr[i];
                xv *= (1.0f / panR[(t0 + j) * 20 + j]);
                xr[j] = xv;
                X[(t0 + j) * 65 + c] = xv;
            }
        }
        __syncthreads();
        int kbeg = q << 6; if (kbeg < t0 + 16) kbeg = t0 + 16;
        int kend = (q << 6) + 64;
        if (kbeg < kend) {
            float xr[16];
            #pragma unroll
            for (int j = 0; j < 16; j++) xr[j] = X[(t0 + j) * 65 + c];
            for (int kk = kbeg; kk < kend; kk++) {
                float rv = X[kk * 65 + c];
                const float4* pr = (const float4*)&panR[kk * 20];
                float4 a = pr[0], b = pr[1], d = pr[2], e = pr[3];
                rv -= a.x * xr[0] + a.y * xr[1] + a.z * xr[2] + a.w * xr[3];
                rv -= b.x * xr[4] + b.y * xr[5] + b.z * xr[6] + b.w * xr[7];
                rv -= d.x * xr[8] + d.y * xr[9] + d.z * xr[10] + d.w * xr[11];
                rv -= e.x * xr[12] + e.y * xr[13] + e.z * xr[14] + e.w * xr[15];
                X[kk * 65 + c] = rv;
            }
        }
        __syncthreads();
    }

    // transposed pair: Tt[jglob][k] = X[k][c]
    for (int idx = tid; idx < 64 * 256; idx += 256) {
        int k = idx & 255, cc = idx >> 8;
        float val = X[k * 65 + cc];
        u16 h, l; cvt2(val, h, l);
        long o = mb + (long)(cb * 64 + cc) * 256 + k;
        dh[o] = h; dl[o] = l;
    }
    // row-major pair for the Kuu set: T[k][jglob] = X[k][c]
    if (mat < S_) {
        for (int idx = tid; idx < 64 * 256; idx += 256) {
            int k = idx >> 6, cc = idx & 63;
            float val = X[k * 65 + cc];
            u16 h, l; cvt2(val, h, l);
            long o = mb + (long)k * 256 + cb * 64 + cc;
            TKrh[o] = h; TKrl[o] = l;
        }
    }
}

// ---------------- pair GEMM: C = alpha * A @ B^T(storage) + epilogue ----------------
// A pair [i][k], B pair [j][k]. K = 256. M, N multiples of 128.

struct PG {
    const u16 *Ah, *Al, *Bh, *Bl;
    float* C; u16 *Ch, *Cl, *ChT, *ClT;
    const float* D; const float* noise;
    const float* kff; float* vfacc;
    int M, N, lda, ldb, ldc, ldct;
    long sA, sB, sC, sP, sCt, sD, sVf, sNoise;
    float alpha, dcoef;
};

template<int OF, int OP, int OPT, int ACCf, int Df, int ADDIf, int EFf, int VFf>
__global__ __launch_bounds__(256) void pgemm_k(PG p) {
    int bz = blockIdx.z;
    const u16* Agh = p.Ah + (long)bz * p.sA;
    const u16* Agl = p.Al + (long)bz * p.sA;
    const u16* Bgh = p.Bh + (long)bz * p.sB;
    const u16* Bgl = p.Bl + (long)bz * p.sB;
    int bm = blockIdx.y * 128, bn = blockIdx.x * 128;
    __shared__ __align__(16) u16 sAh[128][40];
    __shared__ __align__(16) u16 sAl[128][40];
    __shared__ __align__(16) u16 sBh[128][40];
    __shared__ __align__(16) u16 sBl[128][40];
    int tid = threadIdx.x, lane = tid & 63, wid = tid >> 6;
    int wm = (wid >> 1) * 64, wn = (wid & 1) * 64;
    int fr = lane & 15, ko = (lane >> 4) * 8;
    int kb = tid & 3, rw = tid >> 2;
    f32x4 acc[4][4];
    #pragma unroll
    for (int m = 0; m < 4; m++)
        #pragma unroll
        for (int n = 0; n < 4; n++)
            acc[m][n] = (f32x4){0.f, 0.f, 0.f, 0.f};

    for (int k0 = 0; k0 < 256; k0 += 32) {
        #define STG(SRC, LD, BASE, DST) \
            *(bf16x8*)&DST[rw][kb * 8] = \
                *(const bf16x8*)(SRC + (long)(BASE + rw) * LD + k0 + kb * 8); \
            *(bf16x8*)&DST[rw + 64][kb * 8] = \
                *(const bf16x8*)(SRC + (long)(BASE + rw + 64) * LD + k0 + kb * 8);
        STG(Agh, p.lda, bm, sAh)
        STG(Agl, p.lda, bm, sAl)
        STG(Bgh, p.ldb, bn, sBh)
        STG(Bgl, p.ldb, bn, sBl)
        #undef STG
        __syncthreads();
        bf16x8 ah[4], al[4], bh[4], bl[4];
        #pragma unroll
        for (int m = 0; m < 4; m++) {
            ah[m] = *(const bf16x8*)&sAh[wm + m * 16 + fr][ko];
            al[m] = *(const bf16x8*)&sAl[wm + m * 16 + fr][ko];
        }
        #pragma unroll
        for (int n = 0; n < 4; n++) {
            bh[n] = *(const bf16x8*)&sBh[wn + n * 16 + fr][ko];
            bl[n] = *(const bf16x8*)&sBl[wn + n * 16 + fr][ko];
        }
        #pragma unroll
        for (int m = 0; m < 4; m++)
            #pragma unroll
            for (int n = 0; n < 4; n++) {
                acc[m][n] = __builtin_amdgcn_mfma_f32_16x16x32_bf16(ah[m], bh[n], acc[m][n], 0, 0, 0);
                acc[m][n] = __builtin_amdgcn_mfma_f32_16x16x32_bf16(ah[m], bl[n], acc[m][n], 0, 0, 0);
                acc[m][n] = __builtin_amdgcn_mfma_f32_16x16x32_bf16(al[m], bh[n], acc[m][n], 0, 0, 0);
            }
        __syncthreads();
    }

    int rq = (lane >> 4) * 4;
    float rs[4][4];
    if (VFf) {
        #pragma unroll
        for (int m = 0; m < 4; m++)
            #pragma unroll
            for (int i = 0; i < 4; i++) rs[m][i] = 0.f;
    }
    #pragma unroll
    for (int m = 0; m < 4; m++) {
        int row0 = bm + wm + m * 16 + rq;
        #pragma unroll
        for (int n = 0; n < 4; n++) {
            int col = bn + wn + n * 16 + fr;
            float v[4];
            #pragma unroll
            for (int i = 0; i < 4; i++) {
                int r = row0 + i;
                float val = p.alpha * acc[m][n][i];
                if (Df)   val += p.dcoef * p.D[(long)bz * p.sD + (long)r * p.ldc + col];
                if (ACCf) val += p.C[(long)bz * p.sC + (long)r * p.ldc + col];
                if (ADDIf && r == col) val += 1.0f;
                if (EFf) {
                    float kf = p.kff[(long)bz * p.sVf + r];
                    float vq = p.vfacc[(long)bz * p.sVf + r];
                    val += sqrtf(fmaxf(kf - vq, 0.f)) *
                           p.noise[(long)bz * p.sNoise + (long)r * 256 + col];
                }
                v[i] = val;
                if (VFf) rs[m][i] += val * val;
            }
            if (OF) {
                #pragma unroll
                for (int i = 0; i < 4; i++)
                    p.C[(long)bz * p.sC + (long)(row0 + i) * p.ldc + col] = v[i];
            }
            if (OP) {
                #pragma unroll
                for (int i = 0; i < 4; i++) {
                    u16 h, l; cvt2(v[i], h, l);
                    p.Ch[(long)bz * p.sP + (long)(row0 + i) * p.ldc + col] = h;
                    p.Cl[(long)bz * p.sP + (long)(row0 + i) * p.ldc + col] = l;
                }
            }
            if (OPT) {
                u16 h0,h1,h2,h3,l0,l1,l2,l3;
                cvt2(v[0],h0,l0); cvt2(v[1],h1,l1); cvt2(v[2],h2,l2); cvt2(v[3],h3,l3);
                ushort4 hv = {h0,h1,h2,h3}, lv = {l0,l1,l2,l3};
                *(ushort4*)&p.ChT[(long)bz * p.sCt + (long)col * p.ldct + row0] = hv;
                *(ushort4*)&p.ClT[(long)bz * p.sCt + (long)col * p.ldct + row0] = lv;
            }
        }
    }
    if (VFf) {
        #pragma unroll
        for (int m = 0; m < 4; m++) {
            int row0 = bm + wm + m * 16 + rq;
            #pragma unroll
            for (int i = 0; i < 4; i++) {
                float t = rs[m][i];
                t += __shfl_xor(t, 1); t += __shfl_xor(t, 2);
                t += __shfl_xor(t, 4); t += __shfl_xor(t, 8);
                if (fr == 0)
                    atomicAdd(&p.vfacc[(long)bz * p.sVf + row0 + i], t);
            }
        }
    }
}

// ---------------- host ----------------

extern "C" void kernel_launch(void* const* d_in, const int* in_sizes, int n_in,
                              void* d_out, int out_size, void* d_ws, size_t ws_size,
                              hipStream_t stream) {
    const float* Kuu       = (const float*)d_in[0];
    const float* Kuf       = (const float*)d_in[1];
    const float* Kff       = (const float*)d_in[2];
    const float* Lloc      = (const float*)d_in[3];
    const float* Lscale    = (const float*)d_in[4];
    const float* u_param   = (const float*)d_in[5];
    const float* noise_inv = (const float*)d_in[6];
    const float* noise_L   = (const float*)d_in[7];
    const float* noise_f   = (const float*)d_in[8];
    float* out = (float*)d_out;
    float* ws  = (float*)d_ws;

    const long BIG = (long)S_ * MM_;     // 1,048,576 elements
    long off = 1024;
    float* part = ws + 16;

    #define PAIR(NAME, E) u16* NAME##h = (u16*)(ws + off); u16* NAME##l = NAME##h + (E); off += (E);
    PAIR(LS, 65536)          // L (scaled)            [m][m']
    PAIR(LtS, 65536)         // L^T                   [m'][m]
    PAIR(upS, 65536)         // u_param               [o][m]
    PAIR(W1S, 65536)         // up @ L                [o][m']
    float* UPT   = ws + off; off += 65536;   // (L L^T u^T)^T fp32  [o][m]
    float* VfAcc = ws + off; off += 65536;   // ||TK k_f||^2 accumulator
    PAIR(KuuS, BIG)          // slot A: later RHST pair
    PAIR(ninvS, BIG)         // slot B
    PAIR(nLS, BIG)           // slot C: later UT pair
    float* cholK = ws + off; off += BIG;
    PAIR(KuuLS, BIG)         // slot E: later RHS1T fp32
    PAIR(KuuLtS, BIG)        // slot F: later Sigma pair
    float* choll = ws + off; off += BIG;     // slot G: later lKlpIi pair
    PAIR(TKtS, BIG)          // slot H: later UT fp32
    PAIR(TltS, BIG)          // slot I: later Stmp pair
    PAIR(TKrS, BIG)          // TK row-major pair (persists)
    PAIR(G2TS, BIG)          // G2^T pair (persists)
    #undef PAIR

    u16* RHSTh   = KuuSh;            u16* RHSTl   = KuuSl;
    u16* UTph    = nLSh;             u16* UTpl    = nLSl;
    float* RHS1T = (float*)KuuLSh;
    u16* Sigmah  = KuuLtSh;          u16* Sigmal  = KuuLtSl;
    u16* lKlh    = (u16*)choll;      u16* lKll    = lKlh + BIG;
    float* UTf32 = (float*)TKtSh;
    u16* Stmph   = TltSh;            u16* Stmpl   = TltSl;

    long navail = (long)(ws_size / 4) - off;
    long nfc_l = navail / 8192;
    int nfc = (int)((nfc_l / 128) * 128);
    if (nfc > NF_) nfc = NF_;
    if (nfc < 128) nfc = 128;
    long Ec = (long)S_ * nfc * 256;
    u16* KufTch = (u16*)(ws + off);      u16* KufTcl = KufTch + Ec;
    u16* Hch    = (u16*)(ws + off + Ec); u16* Hcl    = Hch + Ec;

    dim3 b256(256);

    // scalars
    max1_kernel<<<256, b256, 0, stream>>>(Kuu, S_ * MM_, part);
    max2_kernel<<<1, b256, 0, stream>>>(part, ws);
    prep_kernel<<<1, b256, 0, stream>>>(Lloc, Lscale, ws);

    // splits
    psplit_kernel<<<1024, b256, 0, stream>>>(Kuu, KuuSh, KuuSl, BIG, nullptr);
    psplit_kernel<<<64, b256, 0, stream>>>(Lloc, LSh, LSl, 65536, ws + 1);
    tsplit_kernel<<<dim3(8, 8, 1), b256, 0, stream>>>(Lloc, 256, 0, LtSh, LtSl, 256, 0, ws + 1);
    psplit_kernel<<<64, b256, 0, stream>>>(u_param, upSh, upSl, 65536, nullptr);
    psplit_kernel<<<1024, b256, 0, stream>>>(noise_inv, ninvSh, ninvSl, BIG, nullptr);
    psplit_kernel<<<1024, b256, 0, stream>>>(noise_L, nLSh, nLSl, BIG, nullptr);
    copyjit_kernel<<<4096, b256, 0, stream>>>(Kuu, ws, cholK);
    hipMemsetAsync(VfAcc, 0, (size_t)S_ * NF_ * sizeof(float), stream);

    PG q;
    auto clr = [&]() {
        q = PG{};
        q.lda = 256; q.ldb = 256; q.ldc = 256; q.ldct = 256;
        q.alpha = 1.f; q.dcoef = 1.f;
        q.M = 256; q.N = 256;
    };

    // a. KuuL = Kuu @ L  -> pair + pairT
    clr(); q.Ah = KuuSh; q.Al = KuuSl; q.sA = MM_;
    q.Bh = LtSh; q.Bl = LtSl; q.sB = 0;
    q.Ch = KuuLSh; q.Cl = KuuLSl; q.sP = MM_;
    q.ChT = KuuLtSh; q.ClT = KuuLtSl; q.sCt = MM_;
    pgemm_k<0,1,1,0,0,0,0,0><<<dim3(2, 2, S_), b256, 0, stream>>>(q);

    // b. choll = KuuL^T @ L + I -> fp32
    clr(); q.Ah = KuuLtSh; q.Al = KuuLtSl; q.sA = MM_;
    q.Bh = LtSh; q.Bl = LtSl; q.sB = 0;
    q.C = choll; q.sC = MM_;
    pgemm_k<1,0,0,0,0,1,0,0><<<dim3(2, 2, S_), b256, 0, stream>>>(q);

    chol_kernel<<<32, dim3(1024), 0, stream>>>(cholK, choll);
    trinv_kernel<<<dim3(4, 32), b256, 0, stream>>>(cholK, choll, TKtSh, TKtSl,
                                                   TltSh, TltSl, TKrSh, TKrSl);

    // d. lKlpIi = Tlt @ Tlt^T -> pair
    clr(); q.Ah = TltSh; q.Al = TltSl; q.sA = MM_;
    q.Bh = TltSh; q.Bl = TltSl; q.sB = MM_;
    q.Ch = lKlh; q.Cl = lKll; q.sP = MM_;
    pgemm_k<0,1,0,0,0,0,0,0><<<dim3(2, 2, S_), b256, 0, stream>>>(q);

    // e. Stmp = KuuL @ lKlpIi -> pair
    clr(); q.Ah = KuuLSh; q.Al = KuuLSl; q.sA = MM_;
    q.Bh = lKlh; q.Bl = lKll; q.sB = MM_;
    q.Ch = Stmph; q.Cl = Stmpl; q.sP = MM_;
    pgemm_k<0,1,0,0,0,0,0,0><<<dim3(2, 2, S_), b256, 0, stream>>>(q);

    // f. Sigma = Kuu - Stmp @ KuuL^T -> pair
    clr(); q.Ah = Stmph; q.Al = Stmpl; q.sA = MM_;
    q.Bh = KuuLSh; q.Bl = KuuLSl; q.sB = MM_;
    q.Ch = Sigmah; q.Cl = Sigmal; q.sP = MM_;
    q.D = Kuu; q.sD = MM_; q.alpha = -1.f;
    pgemm_k<0,1,0,0,1,0,0,0><<<dim3(2, 2, S_), b256, 0, stream>>>(q);

    // g. W1 = up @ L -> pair (batch 1)
    clr(); q.Ah = upSh; q.Al = upSl; q.sA = 0;
    q.Bh = LtSh; q.Bl = LtSl; q.sB = 0;
    q.Ch = W1Sh; q.Cl = W1Sl; q.sP = 0;
    pgemm_k<0,1,0,0,0,0,0,0><<<dim3(2, 2, 1), b256, 0, stream>>>(q);

    // h. UPT = W1 @ L^T -> fp32 (batch 1)
    clr(); q.Ah = W1Sh; q.Al = W1Sl; q.sA = 0;
    q.Bh = LSh; q.Bl = LSl; q.sB = 0;
    q.C = UPT; q.sC = 0;
    pgemm_k<1,0,0,0,0,0,0,0><<<dim3(2, 2, 1), b256, 0, stream>>>(q);

    // i. RHS1T = ninv @ TK + UPT -> fp32
    clr(); q.Ah = ninvSh; q.Al = ninvSl; q.sA = 65536;
    q.Bh = TKtSh; q.Bl = TKtSl; q.sB = MM_;
    q.C = RHS1T; q.sC = MM_;
    q.D = UPT; q.sD = 0;
    pgemm_k<1,0,0,0,1,0,0,0><<<dim3(2, 2, S_), b256, 0, stream>>>(q);

    // j. RHST = nL @ L^T + RHS1T -> pair
    clr(); q.Ah = nLSh; q.Al = nLSl; q.sA = 65536;
    q.Bh = LSh; q.Bl = LSl; q.sB = 0;
    q.C = RHS1T; q.sC = MM_;
    q.Ch = RHSTh; q.Cl = RHSTl; q.sP = MM_;
    pgemm_k<0,1,0,1,0,0,0,0><<<dim3(2, 2, S_), b256, 0, stream>>>(q);

    // k. UT = RHST @ Sigma -> fp32 + pair
    clr(); q.Ah = RHSTh; q.Al = RHSTl; q.sA = MM_;
    q.Bh = Sigmah; q.Bl = Sigmal; q.sB = MM_;
    q.C = UTf32; q.sC = MM_;
    q.Ch = UTph; q.Cl = UTpl; q.sP = MM_;
    pgemm_k<1,1,0,0,0,0,0,0><<<dim3(2, 2, S_), b256, 0, stream>>>(q);

    // G2 = TK @ u -> G2^T pair   (C[m][o] -> stored [o][m])
    clr(); q.Ah = TKrSh; q.Al = TKrSl; q.sA = MM_;
    q.Bh = UTph; q.Bl = UTpl; q.sB = MM_;
    q.ChT = G2TSh; q.ClT = G2TSl; q.sCt = MM_;
    pgemm_k<0,0,1,0,0,0,0,0><<<dim3(2, 2, S_), b256, 0, stream>>>(q);

    // out rows 0..255: out[s][m][o] = UT[s][o][m]
    utrans_kernel<<<dim3(8, 8, S_), b256, 0, stream>>>(UTf32, 256, MM_, out, OUT_, (long)ROWS_ * OUT_);

    for (int f0 = 0; f0 < NF_; f0 += nfc) {
        int w = NF_ - f0; if (w > nfc) w = nfc;
        // KufT chunk pair
        tsplit_kernel<<<dim3(w / 32, 8, S_), b256, 0, stream>>>(
            Kuf + f0, NF_, (long)M_ * NF_, KufTch, KufTcl, 256, (long)w * 256, nullptr);
        // H' = KufT @ TK^T -> pair, + VfAcc[f] += row sums of squares
        clr(); q.M = w; q.N = 256;
        q.Ah = KufTch; q.Al = KufTcl; q.sA = (long)w * 256;
        q.Bh = TKrSh; q.Bl = TKrSl; q.sB = MM_;
        q.Ch = Hch; q.Cl = Hcl; q.sP = (long)w * 256;
        q.vfacc = VfAcc + f0; q.sVf = NF_;
        pgemm_k<0,1,0,0,0,0,0,1><<<dim3(2, w / 128, S_), b256, 0, stream>>>(q);
        // out_f = H' @ G2 + sqrt(Kff - VfAcc)*noise_f
        clr(); q.M = w; q.N = 256;
        q.Ah = Hch; q.Al = Hcl; q.sA = (long)w * 256;
        q.Bh = G2TSh; q.Bl = G2TSl; q.sB = MM_;
        q.C = out + (long)(M_ + f0) * OUT_; q.sC = (long)ROWS_ * OUT_;
        q.kff = Kff + f0; q.vfacc = VfAcc + f0; q.sVf = NF_;
        q.noise = noise_f + (long)f0 * OUT_; q.sNoise = (long)NF_ * OUT_;
        pgemm_k<1,0,0,0,0,0,1,0><<<dim3(2, w / 128, S_), b256, 0, stream>>>(q);
    }
}

// Round 9
// 522.038 us; speedup vs baseline: 1.5861x; 1.1596x over previous
//
#include <hip/hip_runtime.h>
#include <math.h>

#define S_ 16
#define M_ 256
#define NF_ 4096
#define OUT_ 256
#define ROWS_ (M_ + NF_)     // 4352
#define JITTER_ 1e-8f
#define MM_ (M_ * M_)        // 65536

typedef unsigned short u16;
typedef __attribute__((ext_vector_type(8))) short bf16x8;
typedef __attribute__((ext_vector_type(4))) float f32x4;

__device__ inline void cvt2(float x, u16& h, u16& l) {
    unsigned xb = __float_as_uint(x);
    unsigned hb = (xb + 0x7fffu + ((xb >> 16) & 1u)) >> 16;
    float fh = __uint_as_float(hb << 16);
    float rr = x - fh;
    unsigned rb = __float_as_uint(rr);
    unsigned lb = (rb + 0x7fffu + ((rb >> 16) & 1u)) >> 16;
    h = (u16)hb; l = (u16)lb;
}

// ---------------- small prep kernels ----------------

__global__ void max1_kernel(const float* __restrict__ x, int n, float* part) {
    __shared__ float red[256];
    int tid = threadIdx.x;
    float m = -3.4e38f;
    for (int i = blockIdx.x * blockDim.x + tid; i < n; i += gridDim.x * blockDim.x)
        m = fmaxf(m, x[i]);
    red[tid] = m; __syncthreads();
    for (int s = 128; s > 0; s >>= 1) {
        if (tid < s) red[tid] = fmaxf(red[tid], red[tid + s]);
        __syncthreads();
    }
    if (tid == 0) part[blockIdx.x] = red[0];
}

__global__ void max2_kernel(const float* part, float* ws) {
    __shared__ float red[256];
    int tid = threadIdx.x;
    red[tid] = part[tid]; __syncthreads();
    for (int s = 128; s > 0; s >>= 1) {
        if (tid < s) red[tid] = fmaxf(red[tid], red[tid + s]);
        __syncthreads();
    }
    if (tid == 0) { ws[0] = red[0]; ws[2] = JITTER_ * red[0]; }
}

__global__ void prep_kernel(const float* __restrict__ Lloc, const float* __restrict__ Lscale, float* ws) {
    __shared__ float red[256];
    int tid = threadIdx.x;
    red[tid] = Lloc[tid * M_ + tid];
    __syncthreads();
    for (int s = 128; s > 0; s >>= 1) {
        if (tid < s) red[tid] += red[tid + s];
        __syncthreads();
    }
    if (tid == 0) {
        float norm = red[0] / (float)M_;
        ws[1] = expf(Lscale[0]) / norm;
    }
}

__global__ void copyjit_kernel(const float* __restrict__ Kuu, const float* __restrict__ ws, float* __restrict__ dst) {
    int i = blockIdx.x * blockDim.x + threadIdx.x;
    if (i < S_ * MM_) {
        float v = Kuu[i];
        int r = (i >> 8) & 255;
        int c = i & 255;
        if (r == c) v += ws[2];
        dst[i] = v;
    }
}

// ---- plain split: fp32 -> bf16 hi/lo (optional scale from device ptr) ----
__global__ void psplit_kernel(const float* __restrict__ src, u16* __restrict__ h,
                              u16* __restrict__ l, long n, const float* scaleptr) {
    float sc = scaleptr ? scaleptr[0] : 1.0f;
    long stride = (long)gridDim.x * blockDim.x * 4;
    for (long i = ((long)blockIdx.x * blockDim.x + threadIdx.x) * 4; i < n; i += stride) {
        float4 v = *(const float4*)(src + i);
        u16 h0,h1,h2,h3,l0,l1,l2,l3;
        cvt2(v.x*sc,h0,l0); cvt2(v.y*sc,h1,l1); cvt2(v.z*sc,h2,l2); cvt2(v.w*sc,h3,l3);
        ushort4 hv = {h0,h1,h2,h3}, lv = {l0,l1,l2,l3};
        *(ushort4*)(h + i) = hv;
        *(ushort4*)(l + i) = lv;
    }
}

// ---- transpose split: src[r][c] (ldS) -> dst[c][r] (ldD) bf16 hi/lo ----
__global__ void tsplit_kernel(const float* __restrict__ src, int ldS, long sS,
                              u16* __restrict__ h, u16* __restrict__ l, int ldD, long sD,
                              const float* scaleptr) {
    int b = blockIdx.z;
    src += (long)b * sS; h += (long)b * sD; l += (long)b * sD;
    __shared__ float T[32][33];
    int r0 = blockIdx.y * 32, c0 = blockIdx.x * 32;
    float sc = scaleptr ? scaleptr[0] : 1.0f;
    int tid = threadIdx.x;
    int lrow = tid >> 3, lc4 = (tid & 7) * 4;
    float4 v = *(const float4*)(src + (long)(r0 + lrow) * ldS + c0 + lc4);
    T[lrow][lc4 + 0] = v.x * sc; T[lrow][lc4 + 1] = v.y * sc;
    T[lrow][lc4 + 2] = v.z * sc; T[lrow][lc4 + 3] = v.w * sc;
    __syncthreads();
    int wcol = tid >> 3, wr4 = (tid & 7) * 4;
    u16 h0,h1,h2,h3,l0,l1,l2,l3;
    cvt2(T[wr4+0][wcol],h0,l0); cvt2(T[wr4+1][wcol],h1,l1);
    cvt2(T[wr4+2][wcol],h2,l2); cvt2(T[wr4+3][wcol],h3,l3);
    ushort4 hv = {h0,h1,h2,h3}, lv = {l0,l1,l2,l3};
    *(ushort4*)(h + (long)(c0 + wcol) * ldD + r0 + wr4) = hv;
    *(ushort4*)(l + (long)(c0 + wcol) * ldD + r0 + wr4) = lv;
}

// ---- fp32 transpose: dst[c][r] = src[r][c], 32x32 tiles ----
__global__ void utrans_kernel(const float* __restrict__ src, int ldS, long sS,
                              float* __restrict__ dst, int ldD, long sD) {
    int b = blockIdx.z;
    src += (long)b * sS; dst += (long)b * sD;
    __shared__ float T[32][33];
    int r0 = blockIdx.y * 32, c0 = blockIdx.x * 32;
    int tid = threadIdx.x;
    int lrow = tid >> 3, lc4 = (tid & 7) * 4;
    float4 v = *(const float4*)(src + (long)(r0 + lrow) * ldS + c0 + lc4);
    T[lrow][lc4+0]=v.x; T[lrow][lc4+1]=v.y; T[lrow][lc4+2]=v.z; T[lrow][lc4+3]=v.w;
    __syncthreads();
    int wcol = tid >> 3, wr4 = (tid & 7) * 4;
    float4 o;
    o.x = T[wr4+0][wcol]; o.y = T[wr4+1][wcol]; o.z = T[wr4+2][wcol]; o.w = T[wr4+3][wcol];
    *(float4*)(dst + (long)(c0 + wcol) * ldD + r0 + wr4) = o;
}

// ---------------- batched blocked Cholesky (BK=16, 1024 threads) ----------------
// Phase D is chunk-per-thread: cs = tid>>4 owns output chunk column cs, holds
// the 4 B-panel rows (16 float4) in registers, iterates rows r = k0+16+j+16t.
// 6 LDS b128 per 64 FMAs (vs 18 for row-owner scheme).

__global__ __launch_bounds__(1024) void chol_kernel(float* bufA, float* bufB) {
    int blk = blockIdx.x;                       // 0..31
    float* Ag = (blk < S_) ? (bufA + (long)blk * MM_) : (bufB + (long)(blk - S_) * MM_);
    __shared__ float P[33280];                  // 133120 B
    __shared__ float pan2[256 * 20];            // 20480 B  [row][panel col]
    __shared__ float piv[16][18];
    float4* P4 = (float4*)P;
    int tid = threadIdx.x;
    int r = tid >> 2, s = tid & 3;
    int lane = tid & 63, wid = tid >> 6;        // wave w holds rows 16w..16w+15
    int mg = r >> 2, tg = r & 3;
    int b4 = (mg + 1) * (2 * mg + tg);

    for (int i = wid; i < M_; i += 16) {
        int m = i >> 2, t4 = i & 3;
        int rb4 = (m + 1) * (2 * m + t4);
        if (lane <= m) P4[rb4 + lane] = ((const float4*)Ag)[i * 64 + lane];
    }
    __syncthreads();

    float preg[16];
    for (int p = 0; p < 16; p++) {
        int k0 = p << 4;
        int c0 = p << 2;
        #pragma unroll
        for (int rr = 0; rr < 4; rr++) {
            float4 v = make_float4(0.f, 0.f, 0.f, 0.f);
            if (r >= k0 && c0 + rr <= mg) v = P4[b4 + c0 + rr];
            preg[4 * rr + 0] = v.x; preg[4 * rr + 1] = v.y;
            preg[4 * rr + 2] = v.z; preg[4 * rr + 3] = v.w;
        }
        if (wid == p) {
            int dj = lane >> 2;
            float myinv = 0.f;
            #pragma unroll
            for (int j = 0; j < 16; j++) {
                float app = __shfl(preg[j], 4 * j, 64);
                float d = sqrtf(app);
                float inv = 1.0f / d;
                if (dj == j) { preg[j] = d; myinv = inv; }
                else if (dj > j) preg[j] *= inv;
                #pragma unroll
                for (int j2 = j + 1; j2 < 16; j2++) {
                    float Lj2 = __shfl(preg[j], 4 * j2, 64);
                    if (dj >= j2) preg[j2] -= preg[j] * Lj2;
                }
            }
            if (s == 0) {
                #pragma unroll
                for (int i = 0; i < 16; i++) piv[dj][i] = preg[i];
                piv[dj][16] = myinv;
            }
        }
        __syncthreads();
        if (r > k0 + 15) {
            float x[16];
            #pragma unroll
            for (int j = 0; j < 16; j++) {
                float acc = preg[j];
                #pragma unroll
                for (int i = 0; i < 16; i++)
                    if (i < j) acc -= x[i] * piv[j][i];
                x[j] = acc * piv[j][16];
            }
            #pragma unroll
            for (int j = 0; j < 16; j++) preg[j] = x[j];
        }
        if (r >= k0) {
            float4 pv = make_float4(preg[4 * s], preg[4 * s + 1],
                                    preg[4 * s + 2], preg[4 * s + 3]);
            *(float4*)&pan2[r * 20 + 4 * s] = pv;       // row-major publish
            int c = c0 + s;
            if (c <= mg) P4[b4 + c] = pv;
        }
        __syncthreads();
        // ---- (D) chunk-per-thread rank-16 trailing update ----
        {
            int cs = tid >> 4;          // output chunk column 0..63
            int j  = tid & 15;          // row slot
            if (cs >= c0 + 4) {
                float4 q0[4], q1[4], q2[4], q3[4];
                #pragma unroll
                for (int e = 0; e < 4; e++) {
                    const float4* pr = (const float4*)&pan2[(4 * cs + e) * 20];
                    q0[e] = pr[0]; q1[e] = pr[1]; q2[e] = pr[2]; q3[e] = pr[3];
                }
                int rr = k0 + 16 + j;
                int rmin = 4 * cs;
                while (rr < rmin) rr += 16;
                for (; rr < 256; rr += 16) {
                    int mgr = rr >> 2, tgr = rr & 3;
                    int rb4 = (mgr + 1) * (2 * mgr + tgr);
                    const float4* ar = (const float4*)&pan2[rr * 20];
                    float4 a0 = ar[0], a1 = ar[1], a2 = ar[2], a3 = ar[3];
                    float rv[4];
                    *(float4*)rv = P4[rb4 + cs];
                    #pragma unroll
                    for (int e = 0; e < 4; e++) {
                        float acc;
                        acc  = a0.x*q0[e].x + a0.y*q0[e].y + a0.z*q0[e].z + a0.w*q0[e].w;
                        acc += a1.x*q1[e].x + a1.y*q1[e].y + a1.z*q1[e].z + a1.w*q1[e].w;
                        acc += a2.x*q2[e].x + a2.y*q2[e].y + a2.z*q2[e].z + a2.w*q2[e].w;
                        acc += a3.x*q3[e].x + a3.y*q3[e].y + a3.z*q3[e].z + a3.w*q3[e].w;
                        rv[e] -= acc;
                    }
                    P4[rb4 + cs] = *(float4*)rv;
                }
            }
        }
        __syncthreads();
    }

    for (int i = wid; i < M_; i += 16) {
        int m = i >> 2, t4 = i & 3;
        int rb4 = (m + 1) * (2 * m + t4);
        if (lane <= m) ((float4*)Ag)[i * 64 + lane] = P4[rb4 + lane];
    }
}

// ---------------- batched blocked triangular inverse (BK=16) ----------------
// Emits transposed pair Tt[j][k]; for the Kuu set also row-major pair T[k][j].

__global__ __launch_bounds__(256) void trinv_kernel(const float* bufA, const float* bufB,
                                                    u16* TKth, u16* TKtl,
                                                    u16* Tlth, u16* Tltl,
                                                    u16* TKrh, u16* TKrl) {
    int mat = blockIdx.y;      // 0..31
    int cb  = blockIdx.x;      // 0..3
    const float* Lg = (mat < S_) ? (bufA + (long)mat * MM_) : (bufB + (long)(mat - S_) * MM_);
    u16* dh; u16* dl; long mb;
    if (mat < S_) { dh = TKth; dl = TKtl; mb = (long)mat * MM_; }
    else          { dh = Tlth; dl = Tltl; mb = (long)(mat - S_) * MM_; }
    __shared__ float X[M_ * 65];
    __shared__ float panR[M_ * 20];
    int tid = threadIdx.x;
    int c = tid & 63, q = tid >> 6;
    int jglob = cb * 64 + c;

    for (int idx = tid; idx < M_ * 65; idx += 256) X[idx] = 0.f;
    __syncthreads();
    if (q == 0) X[jglob * 65 + c] = 1.0f;

    int p0 = cb * 4;
    for (int p = p0; p < 16; p++) {
        int t0 = p << 4;
        int k = t0 + tid;
        if (k < M_) {
            const float4* src = (const float4*)&Lg[(long)k * M_ + t0];
            float4* dst = (float4*)&panR[k * 20];
            dst[0] = src[0]; dst[1] = src[1]; dst[2] = src[2]; dst[3] = src[3];
        }
        __syncthreads();
        if (q == (t0 >> 6)) {
            float xr[16];
            #pragma unroll
            for (int j = 0; j < 16; j++) {
                float xv = X[(t0 + j) * 65 + c];
                #pragma unroll
                for (int i = 0; i < 16; i++)
                    if (i < j) xv -= panR[(t0 + j) * 20 + i] * xr[i];
                xv *= (1.0f / panR[(t0 + j) * 20 + j]);
                xr[j] = xv;
                X[(t0 + j) * 65 + c] = xv;
            }
        }
        __syncthreads();
        int kbeg = q << 6; if (kbeg < t0 + 16) kbeg = t0 + 16;
        int kend = (q << 6) + 64;
        if (kbeg < kend) {
            float xr[16];
            #pragma unroll
            for (int j = 0; j < 16; j++) xr[j] = X[(t0 + j) * 65 + c];
            for (int kk = kbeg; kk < kend; kk++) {
                float rv = X[kk * 65 + c];
                const float4* pr = (const float4*)&panR[kk * 20];
                float4 a = pr[0], b = pr[1], d = pr[2], e = pr[3];
                rv -= a.x * xr[0] + a.y * xr[1] + a.z * xr[2] + a.w * xr[3];
                rv -= b.x * xr[4] + b.y * xr[5] + b.z * xr[6] + b.w * xr[7];
                rv -= d.x * xr[8] + d.y * xr[9] + d.z * xr[10] + d.w * xr[11];
                rv -= e.x * xr[12] + e.y * xr[13] + e.z * xr[14] + e.w * xr[15];
                X[kk * 65 + c] = rv;
            }
        }
        __syncthreads();
    }

    for (int idx = tid; idx < 64 * 256; idx += 256) {
        int k = idx & 255, cc = idx >> 8;
        float val = X[k * 65 + cc];
        u16 h, l; cvt2(val, h, l);
        long o = mb + (long)(cb * 64 + cc) * 256 + k;
        dh[o] = h; dl[o] = l;
    }
    if (mat < S_) {
        for (int idx = tid; idx < 64 * 256; idx += 256) {
            int k = idx >> 6, cc = idx & 63;
            float val = X[k * 65 + cc];
            u16 h, l; cvt2(val, h, l);
            long o = mb + (long)k * 256 + cb * 64 + cc;
            TKrh[o] = h; TKrl[o] = l;
        }
    }
}

// ---------------- pair GEMM: C = alpha * A @ B^T(storage) + epilogue ----------------

struct PG {
    const u16 *Ah, *Al, *Bh, *Bl;
    float* C; u16 *Ch, *Cl, *ChT, *ClT;
    const float* D; const float* noise;
    const float* kff; float* vfacc;
    int M, N, lda, ldb, ldc, ldct;
    long sA, sB, sC, sP, sCt, sD, sVf, sNoise;
    float alpha, dcoef;
};

// 128x128 tile, 4 waves
template<int OF, int OP, int OPT, int ACCf, int Df, int ADDIf, int EFf, int VFf>
__global__ __launch_bounds__(256) void pgemm_k(PG p) {
    int bz = blockIdx.z;
    const u16* Agh = p.Ah + (long)bz * p.sA;
    const u16* Agl = p.Al + (long)bz * p.sA;
    const u16* Bgh = p.Bh + (long)bz * p.sB;
    const u16* Bgl = p.Bl + (long)bz * p.sB;
    int bm = blockIdx.y * 128, bn = blockIdx.x * 128;
    __shared__ __align__(16) u16 sAh[128][40];
    __shared__ __align__(16) u16 sAl[128][40];
    __shared__ __align__(16) u16 sBh[128][40];
    __shared__ __align__(16) u16 sBl[128][40];
    int tid = threadIdx.x, lane = tid & 63, wid = tid >> 6;
    int wm = (wid >> 1) * 64, wn = (wid & 1) * 64;
    int fr = lane & 15, ko = (lane >> 4) * 8;
    int kb = tid & 3, rw = tid >> 2;
    f32x4 acc[4][4];
    #pragma unroll
    for (int m = 0; m < 4; m++)
        #pragma unroll
        for (int n = 0; n < 4; n++)
            acc[m][n] = (f32x4){0.f, 0.f, 0.f, 0.f};

    for (int k0 = 0; k0 < 256; k0 += 32) {
        #define STG(SRC, LD, BASE, DST) \
            *(bf16x8*)&DST[rw][kb * 8] = \
                *(const bf16x8*)(SRC + (long)(BASE + rw) * LD + k0 + kb * 8); \
            *(bf16x8*)&DST[rw + 64][kb * 8] = \
                *(const bf16x8*)(SRC + (long)(BASE + rw + 64) * LD + k0 + kb * 8);
        STG(Agh, p.lda, bm, sAh)
        STG(Agl, p.lda, bm, sAl)
        STG(Bgh, p.ldb, bn, sBh)
        STG(Bgl, p.ldb, bn, sBl)
        #undef STG
        __syncthreads();
        bf16x8 ah[4], al[4], bh[4], bl[4];
        #pragma unroll
        for (int m = 0; m < 4; m++) {
            ah[m] = *(const bf16x8*)&sAh[wm + m * 16 + fr][ko];
            al[m] = *(const bf16x8*)&sAl[wm + m * 16 + fr][ko];
        }
        #pragma unroll
        for (int n = 0; n < 4; n++) {
            bh[n] = *(const bf16x8*)&sBh[wn + n * 16 + fr][ko];
            bl[n] = *(const bf16x8*)&sBl[wn + n * 16 + fr][ko];
        }
        #pragma unroll
        for (int m = 0; m < 4; m++)
            #pragma unroll
            for (int n = 0; n < 4; n++) {
                acc[m][n] = __builtin_amdgcn_mfma_f32_16x16x32_bf16(ah[m], bh[n], acc[m][n], 0, 0, 0);
                acc[m][n] = __builtin_amdgcn_mfma_f32_16x16x32_bf16(ah[m], bl[n], acc[m][n], 0, 0, 0);
                acc[m][n] = __builtin_amdgcn_mfma_f32_16x16x32_bf16(al[m], bh[n], acc[m][n], 0, 0, 0);
            }
        __syncthreads();
    }

    int rq = (lane >> 4) * 4;
    float rs[4][4];
    if (VFf) {
        #pragma unroll
        for (int m = 0; m < 4; m++)
            #pragma unroll
            for (int i = 0; i < 4; i++) rs[m][i] = 0.f;
    }
    #pragma unroll
    for (int m = 0; m < 4; m++) {
        int row0 = bm + wm + m * 16 + rq;
        #pragma unroll
        for (int n = 0; n < 4; n++) {
            int col = bn + wn + n * 16 + fr;
            float v[4];
            #pragma unroll
            for (int i = 0; i < 4; i++) {
                int r = row0 + i;
                float val = p.alpha * acc[m][n][i];
                if (Df)   val += p.dcoef * p.D[(long)bz * p.sD + (long)r * p.ldc + col];
                if (ACCf) val += p.C[(long)bz * p.sC + (long)r * p.ldc + col];
                if (ADDIf && r == col) val += 1.0f;
                if (EFf) {
                    float kf = p.kff[(long)bz * p.sVf + r];
                    float vq = p.vfacc[(long)bz * p.sVf + r];
                    val += sqrtf(fmaxf(kf - vq, 0.f)) *
                           p.noise[(long)bz * p.sNoise + (long)r * 256 + col];
                }
                v[i] = val;
                if (VFf) rs[m][i] += val * val;
            }
            if (OF) {
                #pragma unroll
                for (int i = 0; i < 4; i++)
                    p.C[(long)bz * p.sC + (long)(row0 + i) * p.ldc + col] = v[i];
            }
            if (OP) {
                #pragma unroll
                for (int i = 0; i < 4; i++) {
                    u16 h, l; cvt2(v[i], h, l);
                    p.Ch[(long)bz * p.sP + (long)(row0 + i) * p.ldc + col] = h;
                    p.Cl[(long)bz * p.sP + (long)(row0 + i) * p.ldc + col] = l;
                }
            }
            if (OPT) {
                u16 h0,h1,h2,h3,l0,l1,l2,l3;
                cvt2(v[0],h0,l0); cvt2(v[1],h1,l1); cvt2(v[2],h2,l2); cvt2(v[3],h3,l3);
                ushort4 hv = {h0,h1,h2,h3}, lv = {l0,l1,l2,l3};
                *(ushort4*)&p.ChT[(long)bz * p.sCt + (long)col * p.ldct + row0] = hv;
                *(ushort4*)&p.ClT[(long)bz * p.sCt + (long)col * p.ldct + row0] = lv;
            }
        }
    }
    if (VFf) {
        #pragma unroll
        for (int m = 0; m < 4; m++) {
            int row0 = bm + wm + m * 16 + rq;
            #pragma unroll
            for (int i = 0; i < 4; i++) {
                float t = rs[m][i];
                t += __shfl_xor(t, 1); t += __shfl_xor(t, 2);
                t += __shfl_xor(t, 4); t += __shfl_xor(t, 8);
                if (fr == 0)
                    atomicAdd(&p.vfacc[(long)bz * p.sVf + row0 + i], t);
            }
        }
    }
}

// 64x64 tile, 4 waves (for the 256^3 GEMMs: 4x more blocks)
template<int OF, int OP, int OPT, int ACCf, int Df, int ADDIf>
__global__ __launch_bounds__(256) void pgemm64_k(PG p) {
    int bz = blockIdx.z;
    const u16* Agh = p.Ah + (long)bz * p.sA;
    const u16* Agl = p.Al + (long)bz * p.sA;
    const u16* Bgh = p.Bh + (long)bz * p.sB;
    const u16* Bgl = p.Bl + (long)bz * p.sB;
    int bm = blockIdx.y * 64, bn = blockIdx.x * 64;
    __shared__ __align__(16) u16 sAh[64][40];
    __shared__ __align__(16) u16 sAl[64][40];
    __shared__ __align__(16) u16 sBh[64][40];
    __shared__ __align__(16) u16 sBl[64][40];
    int tid = threadIdx.x, lane = tid & 63, wid = tid >> 6;
    int wm = (wid >> 1) * 32, wn = (wid & 1) * 32;
    int fr = lane & 15, ko = (lane >> 4) * 8;
    int kb = tid & 3, rw = tid >> 2;
    f32x4 acc[2][2];
    #pragma unroll
    for (int m = 0; m < 2; m++)
        #pragma unroll
        for (int n = 0; n < 2; n++)
            acc[m][n] = (f32x4){0.f, 0.f, 0.f, 0.f};

    for (int k0 = 0; k0 < 256; k0 += 32) {
        *(bf16x8*)&sAh[rw][kb * 8] = *(const bf16x8*)(Agh + (long)(bm + rw) * p.lda + k0 + kb * 8);
        *(bf16x8*)&sAl[rw][kb * 8] = *(const bf16x8*)(Agl + (long)(bm + rw) * p.lda + k0 + kb * 8);
        *(bf16x8*)&sBh[rw][kb * 8] = *(const bf16x8*)(Bgh + (long)(bn + rw) * p.ldb + k0 + kb * 8);
        *(bf16x8*)&sBl[rw][kb * 8] = *(const bf16x8*)(Bgl + (long)(bn + rw) * p.ldb + k0 + kb * 8);
        __syncthreads();
        bf16x8 ah[2], al[2], bh[2], bl[2];
        #pragma unroll
        for (int m = 0; m < 2; m++) {
            ah[m] = *(const bf16x8*)&sAh[wm + m * 16 + fr][ko];
            al[m] = *(const bf16x8*)&sAl[wm + m * 16 + fr][ko];
        }
        #pragma unroll
        for (int n = 0; n < 2; n++) {
            bh[n] = *(const bf16x8*)&sBh[wn + n * 16 + fr][ko];
            bl[n] = *(const bf16x8*)&sBl[wn + n * 16 + fr][ko];
        }
        #pragma unroll
        for (int m = 0; m < 2; m++)
            #pragma unroll
            for (int n = 0; n < 2; n++) {
                acc[m][n] = __builtin_amdgcn_mfma_f32_16x16x32_bf16(ah[m], bh[n], acc[m][n], 0, 0, 0);
                acc[m][n] = __builtin_amdgcn_mfma_f32_16x16x32_bf16(ah[m], bl[n], acc[m][n], 0, 0, 0);
                acc[m][n] = __builtin_amdgcn_mfma_f32_16x16x32_bf16(al[m], bh[n], acc[m][n], 0, 0, 0);
            }
        __syncthreads();
    }

    int rq = (lane >> 4) * 4;
    #pragma unroll
    for (int m = 0; m < 2; m++) {
        int row0 = bm + wm + m * 16 + rq;
        #pragma unroll
        for (int n = 0; n < 2; n++) {
            int col = bn + wn + n * 16 + fr;
            float v[4];
            #pragma unroll
            for (int i = 0; i < 4; i++) {
                int r = row0 + i;
                float val = p.alpha * acc[m][n][i];
                if (Df)   val += p.dcoef * p.D[(long)bz * p.sD + (long)r * p.ldc + col];
                if (ACCf) val += p.C[(long)bz * p.sC + (long)r * p.ldc + col];
                if (ADDIf && r == col) val += 1.0f;
                v[i] = val;
            }
            if (OF) {
                #pragma unroll
                for (int i = 0; i < 4; i++)
                    p.C[(long)bz * p.sC + (long)(row0 + i) * p.ldc + col] = v[i];
            }
            if (OP) {
                #pragma unroll
                for (int i = 0; i < 4; i++) {
                    u16 h, l; cvt2(v[i], h, l);
                    p.Ch[(long)bz * p.sP + (long)(row0 + i) * p.ldc + col] = h;
                    p.Cl[(long)bz * p.sP + (long)(row0 + i) * p.ldc + col] = l;
                }
            }
            if (OPT) {
                u16 h0,h1,h2,h3,l0,l1,l2,l3;
                cvt2(v[0],h0,l0); cvt2(v[1],h1,l1); cvt2(v[2],h2,l2); cvt2(v[3],h3,l3);
                ushort4 hv = {h0,h1,h2,h3}, lv = {l0,l1,l2,l3};
                *(ushort4*)&p.ChT[(long)bz * p.sCt + (long)col * p.ldct + row0] = hv;
                *(ushort4*)&p.ClT[(long)bz * p.sCt + (long)col * p.ldct + row0] = lv;
            }
        }
    }
}

// ---------------- host ----------------

extern "C" void kernel_launch(void* const* d_in, const int* in_sizes, int n_in,
                              void* d_out, int out_size, void* d_ws, size_t ws_size,
                              hipStream_t stream) {
    const float* Kuu       = (const float*)d_in[0];
    const float* Kuf       = (const float*)d_in[1];
    const float* Kff       = (const float*)d_in[2];
    const float* Lloc      = (const float*)d_in[3];
    const float* Lscale    = (const float*)d_in[4];
    const float* u_param   = (const float*)d_in[5];
    const float* noise_inv = (const float*)d_in[6];
    const float* noise_L   = (const float*)d_in[7];
    const float* noise_f   = (const float*)d_in[8];
    float* out = (float*)d_out;
    float* ws  = (float*)d_ws;

    const long BIG = (long)S_ * MM_;     // 1,048,576 elements
    long off = 1024;
    float* part = ws + 16;

    #define PAIR(NAME, E) u16* NAME##h = (u16*)(ws + off); u16* NAME##l = NAME##h + (E); off += (E);
    PAIR(LS, 65536)
    PAIR(LtS, 65536)
    PAIR(upS, 65536)
    PAIR(W1S, 65536)
    float* UPT   = ws + off; off += 65536;
    float* VfAcc = ws + off; off += 65536;
    PAIR(KuuS, BIG)
    PAIR(ninvS, BIG)
    PAIR(nLS, BIG)
    float* cholK = ws + off; off += BIG;
    PAIR(KuuLS, BIG)
    PAIR(KuuLtS, BIG)
    float* choll = ws + off; off += BIG;
    PAIR(TKtS, BIG)
    PAIR(TltS, BIG)
    PAIR(TKrS, BIG)
    PAIR(G2TS, BIG)
    #undef PAIR

    u16* RHSTh   = KuuSh;            u16* RHSTl   = KuuSl;
    u16* UTph    = nLSh;             u16* UTpl    = nLSl;
    float* RHS1T = (float*)KuuLSh;
    u16* Sigmah  = KuuLtSh;          u16* Sigmal  = KuuLtSl;
    u16* lKlh    = (u16*)choll;      u16* lKll    = lKlh + BIG;
    float* UTf32 = (float*)TKtSh;
    u16* Stmph   = TltSh;            u16* Stmpl   = TltSl;

    long navail = (long)(ws_size / 4) - off;
    long nfc_l = navail / 8192;
    int nfc = (int)((nfc_l / 128) * 128);
    if (nfc > NF_) nfc = NF_;
    if (nfc < 128) nfc = 128;
    long Ec = (long)S_ * nfc * 256;
    u16* KufTch = (u16*)(ws + off);      u16* KufTcl = KufTch + Ec;
    u16* Hch    = (u16*)(ws + off + Ec); u16* Hcl    = Hch + Ec;

    dim3 b256(256);

    max1_kernel<<<256, b256, 0, stream>>>(Kuu, S_ * MM_, part);
    max2_kernel<<<1, b256, 0, stream>>>(part, ws);
    prep_kernel<<<1, b256, 0, stream>>>(Lloc, Lscale, ws);

    psplit_kernel<<<1024, b256, 0, stream>>>(Kuu, KuuSh, KuuSl, BIG, nullptr);
    psplit_kernel<<<64, b256, 0, stream>>>(Lloc, LSh, LSl, 65536, ws + 1);
    tsplit_kernel<<<dim3(8, 8, 1), b256, 0, stream>>>(Lloc, 256, 0, LtSh, LtSl, 256, 0, ws + 1);
    psplit_kernel<<<64, b256, 0, stream>>>(u_param, upSh, upSl, 65536, nullptr);
    psplit_kernel<<<1024, b256, 0, stream>>>(noise_inv, ninvSh, ninvSl, BIG, nullptr);
    psplit_kernel<<<1024, b256, 0, stream>>>(noise_L, nLSh, nLSl, BIG, nullptr);
    copyjit_kernel<<<4096, b256, 0, stream>>>(Kuu, ws, cholK);
    hipMemsetAsync(VfAcc, 0, (size_t)S_ * NF_ * sizeof(float), stream);

    PG q;
    auto clr = [&]() {
        q = PG{};
        q.lda = 256; q.ldb = 256; q.ldc = 256; q.ldct = 256;
        q.alpha = 1.f; q.dcoef = 1.f;
        q.M = 256; q.N = 256;
    };
    dim3 g64(4, 4, S_);
    dim3 g64b1(4, 4, 1);

    // a. KuuL = Kuu @ L -> pair + pairT
    clr(); q.Ah = KuuSh; q.Al = KuuSl; q.sA = MM_;
    q.Bh = LtSh; q.Bl = LtSl; q.sB = 0;
    q.Ch = KuuLSh; q.Cl = KuuLSl; q.sP = MM_;
    q.ChT = KuuLtSh; q.ClT = KuuLtSl; q.sCt = MM_;
    pgemm64_k<0,1,1,0,0,0><<<g64, b256, 0, stream>>>(q);

    // b. choll = KuuL^T @ L + I -> fp32
    clr(); q.Ah = KuuLtSh; q.Al = KuuLtSl; q.sA = MM_;
    q.Bh = LtSh; q.Bl = LtSl; q.sB = 0;
    q.C = choll; q.sC = MM_;
    pgemm64_k<1,0,0,0,0,1><<<g64, b256, 0, stream>>>(q);

    chol_kernel<<<32, dim3(1024), 0, stream>>>(cholK, choll);
    trinv_kernel<<<dim3(4, 32), b256, 0, stream>>>(cholK, choll, TKtSh, TKtSl,
                                                   TltSh, TltSl, TKrSh, TKrSl);

    // d. lKlpIi = Tlt @ Tlt^T -> pair
    clr(); q.Ah = TltSh; q.Al = TltSl; q.sA = MM_;
    q.Bh = TltSh; q.Bl = TltSl; q.sB = MM_;
    q.Ch = lKlh; q.Cl = lKll; q.sP = MM_;
    pgemm64_k<0,1,0,0,0,0><<<g64, b256, 0, stream>>>(q);

    // e. Stmp = KuuL @ lKlpIi -> pair
    clr(); q.Ah = KuuLSh; q.Al = KuuLSl; q.sA = MM_;
    q.Bh = lKlh; q.Bl = lKll; q.sB = MM_;
    q.Ch = Stmph; q.Cl = Stmpl; q.sP = MM_;
    pgemm64_k<0,1,0,0,0,0><<<g64, b256, 0, stream>>>(q);

    // f. Sigma = Kuu - Stmp @ KuuL^T -> pair
    clr(); q.Ah = Stmph; q.Al = Stmpl; q.sA = MM_;
    q.Bh = KuuLSh; q.Bl = KuuLSl; q.sB = MM_;
    q.Ch = Sigmah; q.Cl = Sigmal; q.sP = MM_;
    q.D = Kuu; q.sD = MM_; q.alpha = -1.f;
    pgemm64_k<0,1,0,0,1,0><<<g64, b256, 0, stream>>>(q);

    // g. W1 = up @ L -> pair (batch 1)
    clr(); q.Ah = upSh; q.Al = upSl; q.sA = 0;
    q.Bh = LtSh; q.Bl = LtSl; q.sB = 0;
    q.Ch = W1Sh; q.Cl = W1Sl; q.sP = 0;
    pgemm64_k<0,1,0,0,0,0><<<g64b1, b256, 0, stream>>>(q);

    // h. UPT = W1 @ L^T -> fp32 (batch 1)
    clr(); q.Ah = W1Sh; q.Al = W1Sl; q.sA = 0;
    q.Bh = LSh; q.Bl = LSl; q.sB = 0;
    q.C = UPT; q.sC = 0;
    pgemm64_k<1,0,0,0,0,0><<<g64b1, b256, 0, stream>>>(q);

    // i. RHS1T = ninv @ TK + UPT -> fp32
    clr(); q.Ah = ninvSh; q.Al = ninvSl; q.sA = 65536;
    q.Bh = TKtSh; q.Bl = TKtSl; q.sB = MM_;
    q.C = RHS1T; q.sC = MM_;
    q.D = UPT; q.sD = 0;
    pgemm64_k<1,0,0,0,1,0><<<g64, b256, 0, stream>>>(q);

    // j. RHST = nL @ L^T + RHS1T -> pair
    clr(); q.Ah = nLSh; q.Al = nLSl; q.sA = 65536;
    q.Bh = LSh; q.Bl = LSl; q.sB = 0;
    q.C = RHS1T; q.sC = MM_;
    q.Ch = RHSTh; q.Cl = RHSTl; q.sP = MM_;
    pgemm64_k<0,1,0,1,0,0><<<g64, b256, 0, stream>>>(q);

    // k. UT = RHST @ Sigma -> fp32 + pair
    clr(); q.Ah = RHSTh; q.Al = RHSTl; q.sA = MM_;
    q.Bh = Sigmah; q.Bl = Sigmal; q.sB = MM_;
    q.C = UTf32; q.sC = MM_;
    q.Ch = UTph; q.Cl = UTpl; q.sP = MM_;
    pgemm64_k<1,1,0,0,0,0><<<g64, b256, 0, stream>>>(q);

    // G2 = TK @ u -> G2^T pair
    clr(); q.Ah = TKrSh; q.Al = TKrSl; q.sA = MM_;
    q.Bh = UTph; q.Bl = UTpl; q.sB = MM_;
    q.ChT = G2TSh; q.ClT = G2TSl; q.sCt = MM_;
    pgemm64_k<0,0,1,0,0,0><<<g64, b256, 0, stream>>>(q);

    // out rows 0..255
    utrans_kernel<<<dim3(8, 8, S_), b256, 0, stream>>>(UTf32, 256, MM_, out, OUT_, (long)ROWS_ * OUT_);

    for (int f0 = 0; f0 < NF_; f0 += nfc) {
        int w = NF_ - f0; if (w > nfc) w = nfc;
        tsplit_kernel<<<dim3(w / 32, 8, S_), b256, 0, stream>>>(
            Kuf + f0, NF_, (long)M_ * NF_, KufTch, KufTcl, 256, (long)w * 256, nullptr);
        // H' = KufT @ TK^T -> pair, + VfAcc row sums of squares
        clr(); q.M = w; q.N = 256;
        q.Ah = KufTch; q.Al = KufTcl; q.sA = (long)w * 256;
        q.Bh = TKrSh; q.Bl = TKrSl; q.sB = MM_;
        q.Ch = Hch; q.Cl = Hcl; q.sP = (long)w * 256;
        q.vfacc = VfAcc + f0; q.sVf = NF_;
        pgemm_k<0,1,0,0,0,0,0,1><<<dim3(2, w / 128, S_), b256, 0, stream>>>(q);
        // out_f = H' @ G2 + sqrt(Kff - VfAcc)*noise_f
        clr(); q.M = w; q.N = 256;
        q.Ah = Hch; q.Al = Hcl; q.sA = (long)w * 256;
        q.Bh = G2TSh; q.Bl = G2TSl; q.sB = MM_;
        q.C = out + (long)(M_ + f0) * OUT_; q.sC = (long)ROWS_ * OUT_;
        q.kff = Kff + f0; q.vfacc = VfAcc + f0; q.sVf = NF_;
        q.noise = noise_f + (long)f0 * OUT_; q.sNoise = (long)NF_ * OUT_;
        pgemm_k<1,0,0,0,0,0,1,0><<<dim3(2, w / 128, S_), b256, 0, stream>>>(q);
    }
}